// Round 2
// baseline (5667.693 us; speedup 1.0000x reference)
//
#include <hip/hip_runtime.h>
#include <cstdint>
#include <cstddef>

static constexpr int NN = 100000;   // nodes
static constexpr int NE = 1600000;  // edges
static constexpr int NP = 100096;   // NN padded to 128-row GEMM granularity

static constexpr int NBUCK  = 391;  // src buckets (256 nodes each, src>>8)
static constexpr int BCAP   = 5120; // src bucket capacity: mean 4096 + 16 sigma
static constexpr int NBUCKD = 782;  // dst buckets (128 nodes each, dst>>7); 782*128 == NP
static constexpr int BCAPD  = 2816; // dst bucket capacity: mean 2046 + 17 sigma
static constexpr int PBLK   = 200;  // partition blocks
static constexpr int EPB    = 8000; // edges per partition block (PBLK*EPB == NE)

typedef __attribute__((ext_vector_type(8))) short short8;             // 8 bf16 (4 VGPRs)
typedef __attribute__((ext_vector_type(8))) unsigned short ushort8;   // 16B bf16 chunk
typedef __attribute__((ext_vector_type(4))) float f32x4;              // MFMA C/D frag

__device__ inline ushort bf16_rtn(float x) {
    uint32_t u = __float_as_uint(x);
    uint32_t r = u + 0x7fffu + ((u >> 16) & 1u);   // round-to-nearest-even
    return (ushort)(r >> 16);
}
__device__ inline float bf16_to_f(ushort u) {
    return __uint_as_float((uint32_t)u << 16);
}

// ---------------- bucket cursor init ----------------
__global__ __launch_bounds__(256) void k_init_cur(int* __restrict__ curA) {
    int b = blockIdx.x * 256 + threadIdx.x;
    if (b < NBUCK) curA[b] = b * BCAP;
}

// ---------------- phase A: partition edges by SRC bucket ----------------
// pairA = (dst<<8) | (src&255); order within bucket arbitrary (all same 256-src window)
__global__ __launch_bounds__(256) void k_partA(const int* __restrict__ src, const int* __restrict__ dst,
                                               int* __restrict__ curA, int* __restrict__ pairA) {
    __shared__ int hs[NBUCK];
    int e0 = blockIdx.x * EPB;
    for (int i = threadIdx.x; i < NBUCK; i += 256) hs[i] = 0;
    __syncthreads();
    for (int e = e0 + (int)threadIdx.x; e < e0 + EPB; e += 256)
        atomicAdd(&hs[src[e] >> 8], 1);
    __syncthreads();
    for (int i = threadIdx.x; i < NBUCK; i += 256) {
        int c = hs[i];
        hs[i] = c ? atomicAdd(&curA[i], c) : 0;
    }
    __syncthreads();
    for (int e = e0 + (int)threadIdx.x; e < e0 + EPB; e += 256) {
        int s = src[e], d = dst[e];
        int p = atomicAdd(&hs[s >> 8], 1);
        pairA[p] = (d << 8) | (s & 255);
    }
}

// ---------------- out-degree from src buckets ----------------
__global__ __launch_bounds__(256) void k_degout(const int* __restrict__ curA, const int* __restrict__ pairA,
                                                float* __restrict__ deg_out_inv) {
    __shared__ int h[256];
    int b = blockIdx.x;
    int p0 = b * BCAP;
    int n = curA[b] - p0;
    h[threadIdx.x] = 0;
    __syncthreads();
    for (int i = threadIdx.x; i < n; i += 256)
        atomicAdd(&h[pairA[p0 + i] & 255], 1);
    __syncthreads();
    int node = b * 256 + (int)threadIdx.x;
    if (node < NN)
        deg_out_inv[node] = rsqrtf(fmaxf((float)h[threadIdx.x], 1.0f));
}

// ---------------- B1: per-src-bucket histogram of dst buckets ----------------
__global__ __launch_bounds__(256) void k_countB(const int* __restrict__ curA, const int* __restrict__ pairA,
                                                int* __restrict__ cntB) {
    __shared__ int h[NBUCKD];
    int s = blockIdx.x;
    int p0 = s * BCAP;
    int n = curA[s] - p0;
    for (int i = threadIdx.x; i < NBUCKD; i += 256) h[i] = 0;
    __syncthreads();
    for (int i = threadIdx.x; i < n; i += 256)
        atomicAdd(&h[pairA[p0 + i] >> 15], 1);    // dst>>7 == pairA>>15
    __syncthreads();
    for (int i = threadIdx.x; i < NBUCKD; i += 256)
        cntB[s * NBUCKD + i] = h[i];
}

// ---------------- B2: exclusive scan over src buckets per dst bucket ----------------
__global__ __launch_bounds__(512) void k_scanB(const int* __restrict__ cntB, int* __restrict__ offB,
                                               int* __restrict__ fillB) {
    __shared__ int sd[512];
    int b = blockIdx.x;
    int t = threadIdx.x;
    int v = (t < NBUCK) ? cntB[t * NBUCKD + b] : 0;
    sd[t] = v;
    __syncthreads();
    #pragma unroll
    for (int off = 1; off < 512; off <<= 1) {
        int x = (t >= off) ? sd[t - off] : 0;
        __syncthreads();
        sd[t] += x;
        __syncthreads();
    }
    if (t < NBUCK) offB[t * NBUCKD + b] = b * BCAPD + sd[t] - v;
    if (t == NBUCK - 1) fillB[b] = sd[t];
}

// ---------------- B3: deterministic placement -> dst buckets, src-ordered ----------------
// pairB = (src<<7) | (dst&127); within dst bucket, edges ordered by src bucket.
__global__ __launch_bounds__(256) void k_placeB(const int* __restrict__ curA, const int* __restrict__ pairA,
                                                const int* __restrict__ offB, int* __restrict__ pairB) {
    __shared__ int cur[NBUCKD];
    int s = blockIdx.x;
    int p0 = s * BCAP;
    int n = curA[s] - p0;
    for (int i = threadIdx.x; i < NBUCKD; i += 256) cur[i] = offB[s * NBUCKD + i];
    __syncthreads();
    int sbase = s << 8;
    for (int i = threadIdx.x; i < n; i += 256) {
        int pk = pairA[p0 + i];
        int d = pk >> 8;
        int sfull = sbase | (pk & 255);
        int pos = atomicAdd(&cur[d >> 7], 1);
        pairB[pos] = (sfull << 7) | (d & 127);
    }
}

// ---------------- in-degree per dst bucket (covers all NP rows) ----------------
__global__ __launch_bounds__(256) void k_deg_in(const int* __restrict__ fillB, const int* __restrict__ pairB,
                                                float* __restrict__ deg_in_inv) {
    __shared__ int h[128];
    int b = blockIdx.x;
    int p0 = b * BCAPD;
    int n = fillB[b];
    if (threadIdx.x < 128) h[threadIdx.x] = 0;
    __syncthreads();
    for (int i = threadIdx.x; i < n; i += 256)
        atomicAdd(&h[pairB[p0 + i] & 127], 1);
    __syncthreads();
    if (threadIdx.x < 128) {
        int node = b * 128 + (int)threadIdx.x;          // covers exactly NP rows
        deg_in_inv[node] = rsqrtf(fmaxf((float)h[threadIdx.x], 1.0f));
    }
}

// ---------------- feat fp32 -> bf16 with deg_out_inv folded ----------------
__global__ __launch_bounds__(256) void k_cvt(const float* __restrict__ feat,
                                             const float* __restrict__ deg_out_inv,
                                             ushort* __restrict__ out) {
    int idx = blockIdx.x * 256 + threadIdx.x;            // one float4 per thread
    if (idx >= NN * 32) return;                          // NN*128/4
    float4 v = *(const float4*)(feat + (size_t)idx * 4);
    float w = deg_out_inv[idx >> 5];                     // (idx*4)/128
    ushort4 o;
    o.x = bf16_rtn(v.x * w);
    o.y = bf16_rtn(v.y * w);
    o.z = bf16_rtn(v.z * w);
    o.w = bf16_rtn(v.w * w);
    *(ushort4*)(out + (size_t)idx * 4) = o;
}

// ---------------- push aggregation: 128-row dst tile in LDS, src-ordered edge stream --------
// Block = one dst bucket (128 rows), fp32 accumulator 128x128 in LDS (one 128-col pass).
// All blocks sweep src space in lockstep (pairB is src-sorted within bucket) -> gathers
// form a sliding sequential window that stays cache-resident.
template <int XSTRIDE, int COLOFF, bool FINAL>
__global__ __launch_bounds__(512) void k_agg_push(const int* __restrict__ pairB, const int* __restrict__ fillB,
                                                  const ushort* __restrict__ x,
                                                  const float* __restrict__ bias,
                                                  const float* __restrict__ deg_in_inv,
                                                  ushort* __restrict__ out_b, float* __restrict__ out_f) {
    __shared__ float lacc[128 * 128];
    int b = blockIdx.x;
    int p0 = b * BCAPD;
    int n = fillB[b];
    for (int i = threadIdx.x; i < 128 * 128; i += 512) lacc[i] = 0.0f;
    __syncthreads();
    int hw = threadIdx.x >> 5;       // half-wave id 0..15
    int l5 = threadIdx.x & 31;
    #pragma unroll 2
    for (int i = hw; i < n; i += 16) {
        int pk = pairB[p0 + i];
        int row = pk >> 7;
        int dl = pk & 127;
        ushort4 v = *(const ushort4*)(x + (size_t)row * XSTRIDE + COLOFF + l5 * 4);
        float* ap = lacc + dl * 128 + l5 * 4;
        atomicAdd(ap + 0, bf16_to_f(v.x));
        atomicAdd(ap + 1, bf16_to_f(v.y));
        atomicAdd(ap + 2, bf16_to_f(v.z));
        atomicAdd(ap + 3, bf16_to_f(v.w));
    }
    __syncthreads();
    // write back: half-wave h covers rows {h, h+16, ...}; cols l5+32k (bank-conflict-free reads)
    if constexpr (FINAL) {
        float bv[4];
        #pragma unroll
        for (int k = 0; k < 4; ++k) bv[k] = bias[l5 + 32 * k];
        for (int rr = hw; rr < 128; rr += 16) {
            int node = b * 128 + rr;
            if (node < NN) {
                float dv = deg_in_inv[node];
                #pragma unroll
                for (int k = 0; k < 4; ++k)
                    out_f[(size_t)node * 128 + l5 + 32 * k] =
                        (lacc[rr * 128 + l5 + 32 * k] + bv[k]) * dv;
            }
        }
    } else {
        for (int rr = hw; rr < 128; rr += 16) {
            int node = b * 128 + rr;
            ushort* o = out_b + (size_t)node * XSTRIDE + COLOFF;
            #pragma unroll
            for (int k = 0; k < 4; ++k)
                o[l5 + 32 * k] = bf16_rtn(lacc[rr * 128 + l5 + 32 * k]);
        }
    }
}

// ---------------- pack W[K x M] fp32 -> B-fragment-ordered bf16 hi/lo planes ----------------
template <int K, int M>
__device__ inline void packW_dev(const float* __restrict__ W, ushort* __restrict__ out, int blk) {
    constexpr int NT = M / 16, KC = K / 32;
    constexpr int WTOT = KC * NT * 512;      // elements per plane
    int idx = blk * 256 + (int)threadIdx.x;
    int lane = idx & 63;
    int tile = idx >> 6;
    int nt = tile % NT, kc = tile / NT;
    int col = nt * 16 + (lane & 15);
    int kbase = kc * 32 + (lane >> 4) * 8;
    size_t o = (size_t)tile * 512 + lane * 8;
    #pragma unroll
    for (int j = 0; j < 8; ++j) {
        float w = W[(size_t)(kbase + j) * M + col];
        uint32_t u = __float_as_uint(w);
        uint32_t hu = u & 0xffff0000u;
        float lf = w - __uint_as_float(hu);
        out[o + j] = (ushort)(u >> 16);
        out[o + WTOT + j] = (ushort)(__float_as_uint(lf) >> 16);
    }
}

__global__ __launch_bounds__(256) void k_packAll(const float* __restrict__ W1, ushort* __restrict__ o1,
                                                 const float* __restrict__ W2, ushort* __restrict__ o2,
                                                 const float* __restrict__ W3, ushort* __restrict__ o3) {
    int b = blockIdx.x;
    if (b < 16) packW_dev<128, 256>(W1, o1, b);            // 4*16 tiles
    else if (b < 48) packW_dev<256, 256>(W2, o2, b - 16);  // 8*16 tiles
    else packW_dev<256, 128>(W3, o3, b - 48);              // 8*8 tiles
}

// ---------------- bf16 MFMA GEMM, 64x64 wave tiles, fused epilogue ----------------
// MODE 0: out = bf16(A@W)
// MODE 1: out = bf16(prelu(LN((A@W+b)*deg_in)) * deg_out)   [requires M=256]
template <int K, int M, int MODE>
__global__ __launch_bounds__(256) void k_gemm_mfma(const ushort* __restrict__ A,
                                                   const ushort* __restrict__ Wp,
                                                   const float* __restrict__ bias,
                                                   const float* __restrict__ deg_in_inv,
                                                   const float* __restrict__ deg_out_inv,
                                                   const float* __restrict__ g,
                                                   const float* __restrict__ be,
                                                   const float* __restrict__ a,
                                                   ushort* __restrict__ out) {
    constexpr int NT = M / 16;
    constexpr int KC = K / 32;
    constexpr int WTOT = KC * NT * 512;
    constexpr int COLW = M / 64;          // waves across cols (4 for M=256, 2 for M=128)
    constexpr int ROWW = 4 / COLW;        // row groups per block
    constexpr int BROWS = 64 * ROWW;      // rows per block
    constexpr int LROW = M + 8;           // padded LDS row (ushorts)
    __shared__ ushort sbuf[BROWS * LROW];
    __shared__ float sredS[4][64];
    __shared__ float sredQ[4][64];
    __shared__ float smu[64];
    __shared__ float srs[64];

    int lane = threadIdx.x & 63;
    int wave = threadIdx.x >> 6;
    int cw = wave % COLW;                 // col group
    int rw = wave / COLW;                 // row group (0 when M=256)
    int m = lane & 15;
    int quad = lane >> 4;
    int rowb = blockIdx.x * BROWS + rw * 64;

    f32x4 acc[4][4];
    #pragma unroll
    for (int rf = 0; rf < 4; ++rf)
        #pragma unroll
        for (int ct = 0; ct < 4; ++ct) acc[rf][ct] = (f32x4){0.f, 0.f, 0.f, 0.f};

    const ushort* abase = A + (size_t)(rowb + m) * K + quad * 8;
    for (int kc = 0; kc < KC; ++kc) {
        short8 av[4];
        #pragma unroll
        for (int rf = 0; rf < 4; ++rf)
            av[rf] = *(const short8*)(abase + (size_t)rf * 16 * K + kc * 32);
        const ushort* wb0 = Wp + ((size_t)kc * NT + cw * 4) * 512 + lane * 8;
        #pragma unroll
        for (int ct = 0; ct < 4; ++ct) {
            short8 bh = *(const short8*)(wb0 + ct * 512);
            short8 bl = *(const short8*)(wb0 + WTOT + ct * 512);
            #pragma unroll
            for (int rf = 0; rf < 4; ++rf) {
                acc[rf][ct] = __builtin_amdgcn_mfma_f32_16x16x32_bf16(av[rf], bh, acc[rf][ct], 0, 0, 0);
                acc[rf][ct] = __builtin_amdgcn_mfma_f32_16x16x32_bf16(av[rf], bl, acc[rf][ct], 0, 0, 0);
            }
        }
    }
    // acc[rf][ct][r] holds row_local = rw*64 + rf*16 + quad*4 + r, col = cw*64 + ct*16 + m
    if constexpr (MODE == 1) {
        float bia[4];
        #pragma unroll
        for (int ct = 0; ct < 4; ++ct) bia[ct] = bias[cw * 64 + ct * 16 + m];
        float din[4][4], fold[4][4];
        #pragma unroll
        for (int rf = 0; rf < 4; ++rf)
            #pragma unroll
            for (int r = 0; r < 4; ++r) {
                int row = rowb + rf * 16 + quad * 4 + r;
                din[rf][r] = deg_in_inv[row];
                fold[rf][r] = deg_out_inv[row];
            }
        float s[4][4], q[4][4];
        #pragma unroll
        for (int rf = 0; rf < 4; ++rf)
            #pragma unroll
            for (int r = 0; r < 4; ++r) { s[rf][r] = 0.f; q[rf][r] = 0.f; }
        #pragma unroll
        for (int rf = 0; rf < 4; ++rf)
            #pragma unroll
            for (int ct = 0; ct < 4; ++ct)
                #pragma unroll
                for (int r = 0; r < 4; ++r) {
                    float v = (acc[rf][ct][r] + bia[ct]) * din[rf][r];
                    acc[rf][ct][r] = v;
                    s[rf][r] += v;
                    q[rf][r] += v * v;
                }
        #pragma unroll
        for (int w = 1; w < 16; w <<= 1)
            #pragma unroll
            for (int rf = 0; rf < 4; ++rf)
                #pragma unroll
                for (int r = 0; r < 4; ++r) {
                    s[rf][r] += __shfl_xor(s[rf][r], w);
                    q[rf][r] += __shfl_xor(q[rf][r], w);
                }
        if (m == 0) {
            #pragma unroll
            for (int rf = 0; rf < 4; ++rf)
                #pragma unroll
                for (int r = 0; r < 4; ++r) {
                    int rl = rf * 16 + quad * 4 + r;
                    sredS[wave][rl] = s[rf][r];
                    sredQ[wave][rl] = q[rf][r];
                }
        }
        __syncthreads();
        if (threadIdx.x < 64) {
            int rl = threadIdx.x;
            float st = sredS[0][rl] + sredS[1][rl] + sredS[2][rl] + sredS[3][rl];
            float qt = sredQ[0][rl] + sredQ[1][rl] + sredQ[2][rl] + sredQ[3][rl];
            float mu = st * (1.0f / M);
            float var = qt * (1.0f / M) - mu * mu;
            smu[rl] = mu;
            srs[rl] = rsqrtf(var + 1e-5f);
        }
        __syncthreads();
        float alpha = a[0];
        float gv[4], bev[4];
        #pragma unroll
        for (int ct = 0; ct < 4; ++ct) {
            gv[ct] = g[cw * 64 + ct * 16 + m];
            bev[ct] = be[cw * 64 + ct * 16 + m];
        }
        #pragma unroll
        for (int rf = 0; rf < 4; ++rf)
            #pragma unroll
            for (int r = 0; r < 4; ++r) {
                int rl = rf * 16 + quad * 4 + r;
                float mu = smu[rl];
                float rs = srs[rl];
                float fo = fold[rf][r];
                #pragma unroll
                for (int ct = 0; ct < 4; ++ct) {
                    float v = gv[ct] * (acc[rf][ct][r] - mu) * rs + bev[ct];
                    v = (v >= 0.0f) ? v : alpha * v;
                    v *= fo;
                    sbuf[rl * LROW + cw * 64 + ct * 16 + m] = bf16_rtn(v);
                }
            }
    } else {
        #pragma unroll
        for (int rf = 0; rf < 4; ++rf)
            #pragma unroll
            for (int ct = 0; ct < 4; ++ct)
                #pragma unroll
                for (int r = 0; r < 4; ++r)
                    sbuf[(rw * 64 + rf * 16 + quad * 4 + r) * LROW + cw * 64 + ct * 16 + m] =
                        bf16_rtn(acc[rf][ct][r]);
    }
    __syncthreads();
    constexpr int CNT = BROWS * M / 256;        // 64 both cases
    int trow = ((int)threadIdx.x * CNT) / M;
    int tcol = ((int)threadIdx.x * CNT) % M;
    const ushort* rsrc = sbuf + trow * LROW + tcol;
    ushort* gdst = out + (size_t)(blockIdx.x * BROWS + trow) * M + tcol;
    #pragma unroll
    for (int j = 0; j < CNT / 8; ++j) {
        ushort8 v = *(const ushort8*)(rsrc + j * 8);
        *(ushort8*)(gdst + j * 8) = v;
    }
}

extern "C" void kernel_launch(void* const* d_in, const int* in_sizes, int n_in,
                              void* d_out, int out_size, void* d_ws, size_t ws_size,
                              hipStream_t stream) {
    const float* feat = (const float*)d_in[0];
    const float* W1 = (const float*)d_in[1];
    const float* b1 = (const float*)d_in[2];
    const float* g1 = (const float*)d_in[3];
    const float* be1 = (const float*)d_in[4];
    const float* a1 = (const float*)d_in[5];
    const float* W2 = (const float*)d_in[6];
    const float* b2 = (const float*)d_in[7];
    const float* g2 = (const float*)d_in[8];
    const float* be2 = (const float*)d_in[9];
    const float* a2 = (const float*)d_in[10];
    const float* W3 = (const float*)d_in[11];
    const float* b3 = (const float*)d_in[12];
    const int* src = (const int*)d_in[13];
    const int* dst = (const int*)d_in[14];

    char* ws = (char*)d_ws;
    size_t off = 0;
    auto alloc = [&](size_t bytes) -> void* {
        off = (off + 511) & ~(size_t)511;
        void* p = ws + off;
        off += bytes;
        return p;
    };
    int* curA = (int*)alloc((size_t)NBUCK * 4);
    float* deg_out_inv = (float*)alloc((size_t)NP * 4);
    float* deg_in_inv = (float*)alloc((size_t)NP * 4);
    int* pairA = (int*)alloc((size_t)NBUCK * BCAP * 4);
    int* pairB = (int*)alloc((size_t)NBUCKD * BCAPD * 4);
    int* cntB = (int*)alloc((size_t)NBUCK * NBUCKD * 4);
    int* offB = (int*)alloc((size_t)NBUCK * NBUCKD * 4);
    int* fillB = (int*)alloc((size_t)NBUCKD * 4);
    ushort* Wp1 = (ushort*)alloc((size_t)2 * 4 * 16 * 512 * 2);   // K=128,M=256 hi/lo
    ushort* Wp2 = (ushort*)alloc((size_t)2 * 8 * 16 * 512 * 2);   // K=256,M=256
    ushort* Wp3 = (ushort*)alloc((size_t)2 * 8 * 8 * 512 * 2);    // K=256,M=128
    ushort* featb = (ushort*)alloc((size_t)NP * 128 * 2);   // feat*deg_out, bf16
    ushort* aggb  = (ushort*)alloc((size_t)NP * 256 * 2);   // aggregation output (reused)
    ushort* hb    = (ushort*)alloc((size_t)NP * 256 * 2);   // h*deg_out, bf16 (reused)
    ushort* yb    = (ushort*)alloc((size_t)NP * 128 * 2);   // layer-3 GEMM output
    (void)ws_size; (void)in_sizes; (void)n_in; (void)out_size;

    // graph build: src-bucket partition -> deterministic dst partition (src-ordered) -> degrees
    k_init_cur<<<2, 256, 0, stream>>>(curA);
    k_partA<<<PBLK, 256, 0, stream>>>(src, dst, curA, pairA);
    k_degout<<<NBUCK, 256, 0, stream>>>(curA, pairA, deg_out_inv);
    k_countB<<<NBUCK, 256, 0, stream>>>(curA, pairA, cntB);
    k_scanB<<<NBUCKD, 512, 0, stream>>>(cntB, offB, fillB);
    k_placeB<<<NBUCK, 256, 0, stream>>>(curA, pairA, offB, pairB);
    k_deg_in<<<NBUCKD, 256, 0, stream>>>(fillB, pairB, deg_in_inv);

    // weights -> MFMA fragment order (hi/lo planes); feat -> bf16 with deg_out fold
    k_packAll<<<64, 256, 0, stream>>>(W1, Wp1, W2, Wp2, W3, Wp3);
    k_cvt<<<(NN * 32 + 255) / 256, 256, 0, stream>>>(feat, deg_out_inv, featb);

    // layer 1: push-agg(feat*deg_out) -> GEMM 128->256 [+b1,*deg_in,LN,PReLU,*deg_out] -> hb
    k_agg_push<128, 0, false><<<NBUCKD, 512, 0, stream>>>(pairB, fillB, featb, nullptr, nullptr, aggb, nullptr);
    k_gemm_mfma<128, 256, 1><<<NP / 64, 256, 0, stream>>>(aggb, Wp1, b1, deg_in_inv, deg_out_inv, g1, be1, a1, hb);

    // layer 2: push-agg(h1*deg_out) in two 128-col passes -> GEMM 256->256 [epilogue] -> hb
    k_agg_push<256, 0, false><<<NBUCKD, 512, 0, stream>>>(pairB, fillB, hb, nullptr, nullptr, aggb, nullptr);
    k_agg_push<256, 128, false><<<NBUCKD, 512, 0, stream>>>(pairB, fillB, hb, nullptr, nullptr, aggb, nullptr);
    k_gemm_mfma<256, 256, 1><<<NP / 64, 256, 0, stream>>>(aggb, Wp2, b2, deg_in_inv, deg_out_inv, g2, be2, a2, hb);

    // layer 3: GEMM (h2*deg_out)@W3 -> yb, then push-agg(yb) with (+b3)*deg_in into d_out
    k_gemm_mfma<256, 128, 0><<<NP / 128, 256, 0, stream>>>(hb, Wp3, nullptr, nullptr, nullptr, nullptr, nullptr, nullptr, yb);
    k_agg_push<128, 0, true><<<NBUCKD, 512, 0, stream>>>(pairB, fillB, yb, b3, deg_in_inv, nullptr, (float*)d_out);
}

// Round 3
// 696.190 us; speedup vs baseline: 8.1410x; 8.1410x over previous
//
#include <hip/hip_runtime.h>
#include <cstdint>
#include <cstddef>

static constexpr int NN = 100000;   // nodes
static constexpr int NE = 1600000;  // edges
static constexpr int NP = 100096;   // NN padded to 128-row GEMM granularity

static constexpr int NBUCK  = 391;  // src buckets (256 nodes each, src>>8)
static constexpr int BCAP   = 5120; // src bucket capacity: mean 4096 + 16 sigma
static constexpr int NBUCKD = 782;  // dst buckets (128 nodes each, dst>>7); 782*128 == NP
static constexpr int BCAPD  = 2816; // dst bucket capacity: mean 2046 + 17 sigma
static constexpr int SCAP   = 448;  // sub-list capacity: mean 256 + 12 sigma
static constexpr int PBLK   = 200;  // partition blocks
static constexpr int EPB    = 8000; // edges per partition block (PBLK*EPB == NE)

typedef __attribute__((ext_vector_type(8))) short short8;             // 8 bf16 (4 VGPRs)
typedef __attribute__((ext_vector_type(8))) unsigned short ushort8;   // 16B bf16 chunk
typedef __attribute__((ext_vector_type(4))) float f32x4;              // MFMA C/D frag

__device__ inline ushort bf16_rtn(float x) {
    uint32_t u = __float_as_uint(x);
    uint32_t r = u + 0x7fffu + ((u >> 16) & 1u);   // round-to-nearest-even
    return (ushort)(r >> 16);
}
__device__ inline float bf16_to_f(ushort u) {
    return __uint_as_float((uint32_t)u << 16);
}

// ---------------- bucket cursor init ----------------
__global__ __launch_bounds__(256) void k_init_cur(int* __restrict__ curA) {
    int b = blockIdx.x * 256 + threadIdx.x;
    if (b < NBUCK) curA[b] = b * BCAP;
}

// ---------------- phase A: partition edges by SRC bucket ----------------
// pairA = (dst<<8) | (src&255); order within bucket arbitrary (all same 256-src window)
__global__ __launch_bounds__(256) void k_partA(const int* __restrict__ src, const int* __restrict__ dst,
                                               int* __restrict__ curA, int* __restrict__ pairA) {
    __shared__ int hs[NBUCK];
    int e0 = blockIdx.x * EPB;
    for (int i = threadIdx.x; i < NBUCK; i += 256) hs[i] = 0;
    __syncthreads();
    for (int e = e0 + (int)threadIdx.x; e < e0 + EPB; e += 256)
        atomicAdd(&hs[src[e] >> 8], 1);
    __syncthreads();
    for (int i = threadIdx.x; i < NBUCK; i += 256) {
        int c = hs[i];
        hs[i] = c ? atomicAdd(&curA[i], c) : 0;
    }
    __syncthreads();
    for (int e = e0 + (int)threadIdx.x; e < e0 + EPB; e += 256) {
        int s = src[e], d = dst[e];
        int p = atomicAdd(&hs[s >> 8], 1);
        pairA[p] = (d << 8) | (s & 255);
    }
}

// ---------------- out-degree from src buckets ----------------
__global__ __launch_bounds__(256) void k_degout(const int* __restrict__ curA, const int* __restrict__ pairA,
                                                float* __restrict__ deg_out_inv) {
    __shared__ int h[256];
    int b = blockIdx.x;
    int p0 = b * BCAP;
    int n = curA[b] - p0;
    h[threadIdx.x] = 0;
    __syncthreads();
    for (int i = threadIdx.x; i < n; i += 256)
        atomicAdd(&h[pairA[p0 + i] & 255], 1);
    __syncthreads();
    int node = b * 256 + (int)threadIdx.x;
    if (node < NN)
        deg_out_inv[node] = rsqrtf(fmaxf((float)h[threadIdx.x], 1.0f));
}

// ---------------- B1: per-src-bucket histogram of dst buckets ----------------
__global__ __launch_bounds__(256) void k_countB(const int* __restrict__ curA, const int* __restrict__ pairA,
                                                int* __restrict__ cntB) {
    __shared__ int h[NBUCKD];
    int s = blockIdx.x;
    int p0 = s * BCAP;
    int n = curA[s] - p0;
    for (int i = threadIdx.x; i < NBUCKD; i += 256) h[i] = 0;
    __syncthreads();
    for (int i = threadIdx.x; i < n; i += 256)
        atomicAdd(&h[pairA[p0 + i] >> 15], 1);    // dst>>7 == pairA>>15
    __syncthreads();
    for (int i = threadIdx.x; i < NBUCKD; i += 256)
        cntB[s * NBUCKD + i] = h[i];
}

// ---------------- B2: exclusive scan over src buckets per dst bucket ----------------
__global__ __launch_bounds__(512) void k_scanB(const int* __restrict__ cntB, int* __restrict__ offB,
                                               int* __restrict__ fillB) {
    __shared__ int sd[512];
    int b = blockIdx.x;
    int t = threadIdx.x;
    int v = (t < NBUCK) ? cntB[t * NBUCKD + b] : 0;
    sd[t] = v;
    __syncthreads();
    #pragma unroll
    for (int off = 1; off < 512; off <<= 1) {
        int x = (t >= off) ? sd[t - off] : 0;
        __syncthreads();
        sd[t] += x;
        __syncthreads();
    }
    if (t < NBUCK) offB[t * NBUCKD + b] = b * BCAPD + sd[t] - v;
    if (t == NBUCK - 1) fillB[b] = sd[t];
}

// ---------------- B3: deterministic placement -> dst buckets, src-ordered ----------------
// pairB = (src<<7) | (dst&127); within dst bucket, edges ordered by src bucket.
__global__ __launch_bounds__(256) void k_placeB(const int* __restrict__ curA, const int* __restrict__ pairA,
                                                const int* __restrict__ offB, int* __restrict__ pairB) {
    __shared__ int cur[NBUCKD];
    int s = blockIdx.x;
    int p0 = s * BCAP;
    int n = curA[s] - p0;
    for (int i = threadIdx.x; i < NBUCKD; i += 256) cur[i] = offB[s * NBUCKD + i];
    __syncthreads();
    int sbase = s << 8;
    for (int i = threadIdx.x; i < n; i += 256) {
        int pk = pairA[p0 + i];
        int d = pk >> 8;
        int sfull = sbase | (pk & 255);
        int pos = atomicAdd(&cur[d >> 7], 1);
        pairB[pos] = (sfull << 7) | (d & 127);
    }
}

// ---------------- in-degree per dst bucket (covers all NP rows) ----------------
__global__ __launch_bounds__(256) void k_deg_in(const int* __restrict__ fillB, const int* __restrict__ pairB,
                                                float* __restrict__ deg_in_inv) {
    __shared__ int h[128];
    int b = blockIdx.x;
    int p0 = b * BCAPD;
    int n = fillB[b];
    if (threadIdx.x < 128) h[threadIdx.x] = 0;
    __syncthreads();
    for (int i = threadIdx.x; i < n; i += 256)
        atomicAdd(&h[pairB[p0 + i] & 127], 1);
    __syncthreads();
    if (threadIdx.x < 128) {
        int node = b * 128 + (int)threadIdx.x;          // covers exactly NP rows
        deg_in_inv[node] = rsqrtf(fmaxf((float)h[threadIdx.x], 1.0f));
    }
}

// ---------------- stable split of each dst bucket into 8 sub-lists by dl&7 ----------------
// Wave w extracts edges with (dl&7)==w, preserving src order (ballot + prefix-popc).
// Enables atomic-free LDS accumulation: wave w exclusively owns rows dl&7==w.
__global__ __launch_bounds__(512) void k_split8(const int* __restrict__ fillB, const int* __restrict__ pairB,
                                                int* __restrict__ pairB2, int* __restrict__ fillS) {
    int b = blockIdx.x;
    int w = threadIdx.x >> 6;
    int l = threadIdx.x & 63;
    int n = fillB[b];
    const int* ep = pairB + (size_t)b * BCAPD;
    int* op = pairB2 + (size_t)(b * 8 + w) * SCAP;
    int cnt = 0;
    for (int i0 = 0; i0 < n; i0 += 64) {
        int idx = i0 + l;
        int pk = (idx < n) ? ep[idx] : 0;
        bool match = (idx < n) && ((pk & 7) == w);   // pk&7 == dl&7
        unsigned long long mask = __ballot(match);
        if (match) {
            int pos = __popcll(mask & ((1ull << l) - 1ull));
            op[cnt + pos] = pk;
        }
        cnt += __popcll(mask);
    }
    if (l == 0) fillS[b * 8 + w] = cnt;
}

// ---------------- feat fp32 -> bf16 with deg_out_inv folded ----------------
__global__ __launch_bounds__(256) void k_cvt(const float* __restrict__ feat,
                                             const float* __restrict__ deg_out_inv,
                                             ushort* __restrict__ out) {
    int idx = blockIdx.x * 256 + threadIdx.x;            // one float4 per thread
    if (idx >= NN * 32) return;                          // NN*128/4
    float4 v = *(const float4*)(feat + (size_t)idx * 4);
    float w = deg_out_inv[idx >> 5];                     // (idx*4)/128
    ushort4 o;
    o.x = bf16_rtn(v.x * w);
    o.y = bf16_rtn(v.y * w);
    o.z = bf16_rtn(v.z * w);
    o.w = bf16_rtn(v.w * w);
    *(ushort4*)(out + (size_t)idx * 4) = o;
}

// ---------------- atomic-free push aggregation ----------------
// Block = one dst bucket (128 rows), 8 waves; wave w owns rows with dl&7==w and walks
// its src-sorted sub-list: per edge one coalesced 256B gather (ushort2/lane) + plain
// LDS float2 RMW (no atomics; same-row edges within a wave serialize via program order).
// All blocks sweep src space in lockstep -> gathers stay cache-resident.
template <int XSTRIDE, int COLOFF, bool FINAL>
__global__ __launch_bounds__(512) void k_agg_push2(const int* __restrict__ pairB2, const int* __restrict__ fillS,
                                                   const ushort* __restrict__ x,
                                                   const float* __restrict__ bias,
                                                   const float* __restrict__ deg_in_inv,
                                                   ushort* __restrict__ out_b, float* __restrict__ out_f) {
    __shared__ float lacc[128 * 128];
    int b = blockIdx.x;
    for (int i = threadIdx.x; i < 4096; i += 512)
        *(float4*)&lacc[i * 4] = (float4){0.f, 0.f, 0.f, 0.f};
    __syncthreads();
    int w = threadIdx.x >> 6;
    int l = threadIdx.x & 63;
    int sb = b * 8 + w;
    int m = fillS[sb];
    const int* ep = pairB2 + (size_t)sb * SCAP;
    const ushort* xb = x + COLOFF + 2 * l;
    int i = 0;
    for (; i + 8 <= m; i += 8) {
        int pk[8];
        #pragma unroll
        for (int j = 0; j < 8; ++j) pk[j] = ep[i + j];
        ushort2 v[8];
        #pragma unroll
        for (int j = 0; j < 8; ++j)
            v[j] = *(const ushort2*)(xb + (size_t)(pk[j] >> 7) * XSTRIDE);
        #pragma unroll
        for (int j = 0; j < 8; ++j) {
            int a = (pk[j] & 127) * 128 + 2 * l;
            float2 c = *(float2*)&lacc[a];
            c.x += bf16_to_f(v[j].x);
            c.y += bf16_to_f(v[j].y);
            *(float2*)&lacc[a] = c;
        }
    }
    for (; i < m; ++i) {
        int pk = ep[i];
        ushort2 vv = *(const ushort2*)(xb + (size_t)(pk >> 7) * XSTRIDE);
        int a = (pk & 127) * 128 + 2 * l;
        float2 c = *(float2*)&lacc[a];
        c.x += bf16_to_f(vv.x);
        c.y += bf16_to_f(vv.y);
        *(float2*)&lacc[a] = c;
    }
    __syncthreads();
    // writeback: wave w covers rows w*16..w*16+15; lane covers cols {2l, 2l+1}
    if constexpr (FINAL) {
        float2 bv = *(const float2*)(bias + 2 * l);
        #pragma unroll 4
        for (int rr = 0; rr < 16; ++rr) {
            int rl = w * 16 + rr;
            int node = b * 128 + rl;
            if (node < NN) {
                float dv = deg_in_inv[node];
                float2 c = *(float2*)&lacc[rl * 128 + 2 * l];
                float2 o;
                o.x = (c.x + bv.x) * dv;
                o.y = (c.y + bv.y) * dv;
                *(float2*)(out_f + (size_t)node * 128 + 2 * l) = o;
            }
        }
    } else {
        #pragma unroll 4
        for (int rr = 0; rr < 16; ++rr) {
            int rl = w * 16 + rr;
            int node = b * 128 + rl;          // < NP always; pad rows get zeros
            float2 c = *(float2*)&lacc[rl * 128 + 2 * l];
            ushort2 o;
            o.x = bf16_rtn(c.x);
            o.y = bf16_rtn(c.y);
            *(ushort2*)(out_b + (size_t)node * XSTRIDE + COLOFF + 2 * l) = o;
        }
    }
}

// ---------------- pack W[K x M] fp32 -> B-fragment-ordered bf16 hi/lo planes ----------------
template <int K, int M>
__device__ inline void packW_dev(const float* __restrict__ W, ushort* __restrict__ out, int blk) {
    constexpr int NT = M / 16, KC = K / 32;
    constexpr int WTOT = KC * NT * 512;      // elements per plane
    int idx = blk * 256 + (int)threadIdx.x;
    int lane = idx & 63;
    int tile = idx >> 6;
    int nt = tile % NT, kc = tile / NT;
    int col = nt * 16 + (lane & 15);
    int kbase = kc * 32 + (lane >> 4) * 8;
    size_t o = (size_t)tile * 512 + lane * 8;
    #pragma unroll
    for (int j = 0; j < 8; ++j) {
        float w = W[(size_t)(kbase + j) * M + col];
        uint32_t u = __float_as_uint(w);
        uint32_t hu = u & 0xffff0000u;
        float lf = w - __uint_as_float(hu);
        out[o + j] = (ushort)(u >> 16);
        out[o + WTOT + j] = (ushort)(__float_as_uint(lf) >> 16);
    }
}

__global__ __launch_bounds__(256) void k_packAll(const float* __restrict__ W1, ushort* __restrict__ o1,
                                                 const float* __restrict__ W2, ushort* __restrict__ o2,
                                                 const float* __restrict__ W3, ushort* __restrict__ o3) {
    int b = blockIdx.x;
    if (b < 16) packW_dev<128, 256>(W1, o1, b);            // 4*16 tiles
    else if (b < 48) packW_dev<256, 256>(W2, o2, b - 16);  // 8*16 tiles
    else packW_dev<256, 128>(W3, o3, b - 48);              // 8*8 tiles
}

// ---------------- bf16 MFMA GEMM, 64x64 wave tiles, fused epilogue ----------------
// MODE 0: out = bf16(A@W)
// MODE 1: out = bf16(prelu(LN((A@W+b)*deg_in)) * deg_out)   [requires M=256]
template <int K, int M, int MODE>
__global__ __launch_bounds__(256) void k_gemm_mfma(const ushort* __restrict__ A,
                                                   const ushort* __restrict__ Wp,
                                                   const float* __restrict__ bias,
                                                   const float* __restrict__ deg_in_inv,
                                                   const float* __restrict__ deg_out_inv,
                                                   const float* __restrict__ g,
                                                   const float* __restrict__ be,
                                                   const float* __restrict__ a,
                                                   ushort* __restrict__ out) {
    constexpr int NT = M / 16;
    constexpr int KC = K / 32;
    constexpr int WTOT = KC * NT * 512;
    constexpr int COLW = M / 64;          // waves across cols (4 for M=256, 2 for M=128)
    constexpr int ROWW = 4 / COLW;        // row groups per block
    constexpr int BROWS = 64 * ROWW;      // rows per block
    constexpr int LROW = M + 8;           // padded LDS row (ushorts)
    __shared__ ushort sbuf[BROWS * LROW];
    __shared__ float sredS[4][64];
    __shared__ float sredQ[4][64];
    __shared__ float smu[64];
    __shared__ float srs[64];

    int lane = threadIdx.x & 63;
    int wave = threadIdx.x >> 6;
    int cw = wave % COLW;                 // col group
    int rw = wave / COLW;                 // row group (0 when M=256)
    int m = lane & 15;
    int quad = lane >> 4;
    int rowb = blockIdx.x * BROWS + rw * 64;

    f32x4 acc[4][4];
    #pragma unroll
    for (int rf = 0; rf < 4; ++rf)
        #pragma unroll
        for (int ct = 0; ct < 4; ++ct) acc[rf][ct] = (f32x4){0.f, 0.f, 0.f, 0.f};

    const ushort* abase = A + (size_t)(rowb + m) * K + quad * 8;
    for (int kc = 0; kc < KC; ++kc) {
        short8 av[4];
        #pragma unroll
        for (int rf = 0; rf < 4; ++rf)
            av[rf] = *(const short8*)(abase + (size_t)rf * 16 * K + kc * 32);
        const ushort* wb0 = Wp + ((size_t)kc * NT + cw * 4) * 512 + lane * 8;
        #pragma unroll
        for (int ct = 0; ct < 4; ++ct) {
            short8 bh = *(const short8*)(wb0 + ct * 512);
            short8 bl = *(const short8*)(wb0 + WTOT + ct * 512);
            #pragma unroll
            for (int rf = 0; rf < 4; ++rf) {
                acc[rf][ct] = __builtin_amdgcn_mfma_f32_16x16x32_bf16(av[rf], bh, acc[rf][ct], 0, 0, 0);
                acc[rf][ct] = __builtin_amdgcn_mfma_f32_16x16x32_bf16(av[rf], bl, acc[rf][ct], 0, 0, 0);
            }
        }
    }
    // acc[rf][ct][r] holds row_local = rw*64 + rf*16 + quad*4 + r, col = cw*64 + ct*16 + m
    if constexpr (MODE == 1) {
        float bia[4];
        #pragma unroll
        for (int ct = 0; ct < 4; ++ct) bia[ct] = bias[cw * 64 + ct * 16 + m];
        float din[4][4], fold[4][4];
        #pragma unroll
        for (int rf = 0; rf < 4; ++rf)
            #pragma unroll
            for (int r = 0; r < 4; ++r) {
                int row = rowb + rf * 16 + quad * 4 + r;
                din[rf][r] = deg_in_inv[row];
                fold[rf][r] = deg_out_inv[row];
            }
        float s[4][4], q[4][4];
        #pragma unroll
        for (int rf = 0; rf < 4; ++rf)
            #pragma unroll
            for (int r = 0; r < 4; ++r) { s[rf][r] = 0.f; q[rf][r] = 0.f; }
        #pragma unroll
        for (int rf = 0; rf < 4; ++rf)
            #pragma unroll
            for (int ct = 0; ct < 4; ++ct)
                #pragma unroll
                for (int r = 0; r < 4; ++r) {
                    float v = (acc[rf][ct][r] + bia[ct]) * din[rf][r];
                    acc[rf][ct][r] = v;
                    s[rf][r] += v;
                    q[rf][r] += v * v;
                }
        #pragma unroll
        for (int w = 1; w < 16; w <<= 1)
            #pragma unroll
            for (int rf = 0; rf < 4; ++rf)
                #pragma unroll
                for (int r = 0; r < 4; ++r) {
                    s[rf][r] += __shfl_xor(s[rf][r], w);
                    q[rf][r] += __shfl_xor(q[rf][r], w);
                }
        if (m == 0) {
            #pragma unroll
            for (int rf = 0; rf < 4; ++rf)
                #pragma unroll
                for (int r = 0; r < 4; ++r) {
                    int rl = rf * 16 + quad * 4 + r;
                    sredS[wave][rl] = s[rf][r];
                    sredQ[wave][rl] = q[rf][r];
                }
        }
        __syncthreads();
        if (threadIdx.x < 64) {
            int rl = threadIdx.x;
            float st = sredS[0][rl] + sredS[1][rl] + sredS[2][rl] + sredS[3][rl];
            float qt = sredQ[0][rl] + sredQ[1][rl] + sredQ[2][rl] + sredQ[3][rl];
            float mu = st * (1.0f / M);
            float var = qt * (1.0f / M) - mu * mu;
            smu[rl] = mu;
            srs[rl] = rsqrtf(var + 1e-5f);
        }
        __syncthreads();
        float alpha = a[0];
        float gv[4], bev[4];
        #pragma unroll
        for (int ct = 0; ct < 4; ++ct) {
            gv[ct] = g[cw * 64 + ct * 16 + m];
            bev[ct] = be[cw * 64 + ct * 16 + m];
        }
        #pragma unroll
        for (int rf = 0; rf < 4; ++rf)
            #pragma unroll
            for (int r = 0; r < 4; ++r) {
                int rl = rf * 16 + quad * 4 + r;
                float mu = smu[rl];
                float rs = srs[rl];
                float fo = fold[rf][r];
                #pragma unroll
                for (int ct = 0; ct < 4; ++ct) {
                    float v = gv[ct] * (acc[rf][ct][r] - mu) * rs + bev[ct];
                    v = (v >= 0.0f) ? v : alpha * v;
                    v *= fo;
                    sbuf[rl * LROW + cw * 64 + ct * 16 + m] = bf16_rtn(v);
                }
            }
    } else {
        #pragma unroll
        for (int rf = 0; rf < 4; ++rf)
            #pragma unroll
            for (int ct = 0; ct < 4; ++ct)
                #pragma unroll
                for (int r = 0; r < 4; ++r)
                    sbuf[(rw * 64 + rf * 16 + quad * 4 + r) * LROW + cw * 64 + ct * 16 + m] =
                        bf16_rtn(acc[rf][ct][r]);
    }
    __syncthreads();
    constexpr int CNT = BROWS * M / 256;        // 64 both cases
    int trow = ((int)threadIdx.x * CNT) / M;
    int tcol = ((int)threadIdx.x * CNT) % M;
    const ushort* rsrc = sbuf + trow * LROW + tcol;
    ushort* gdst = out + (size_t)(blockIdx.x * BROWS + trow) * M + tcol;
    #pragma unroll
    for (int j = 0; j < CNT / 8; ++j) {
        ushort8 v = *(const ushort8*)(rsrc + j * 8);
        *(ushort8*)(gdst + j * 8) = v;
    }
}

extern "C" void kernel_launch(void* const* d_in, const int* in_sizes, int n_in,
                              void* d_out, int out_size, void* d_ws, size_t ws_size,
                              hipStream_t stream) {
    const float* feat = (const float*)d_in[0];
    const float* W1 = (const float*)d_in[1];
    const float* b1 = (const float*)d_in[2];
    const float* g1 = (const float*)d_in[3];
    const float* be1 = (const float*)d_in[4];
    const float* a1 = (const float*)d_in[5];
    const float* W2 = (const float*)d_in[6];
    const float* b2 = (const float*)d_in[7];
    const float* g2 = (const float*)d_in[8];
    const float* be2 = (const float*)d_in[9];
    const float* a2 = (const float*)d_in[10];
    const float* W3 = (const float*)d_in[11];
    const float* b3 = (const float*)d_in[12];
    const int* src = (const int*)d_in[13];
    const int* dst = (const int*)d_in[14];

    char* ws = (char*)d_ws;
    size_t off = 0;
    auto alloc = [&](size_t bytes) -> void* {
        off = (off + 511) & ~(size_t)511;
        void* p = ws + off;
        off += bytes;
        return p;
    };
    int* curA = (int*)alloc((size_t)NBUCK * 4);
    float* deg_out_inv = (float*)alloc((size_t)NP * 4);
    float* deg_in_inv = (float*)alloc((size_t)NP * 4);
    int* pairA = (int*)alloc((size_t)NBUCK * BCAP * 4);
    int* pairB = (int*)alloc((size_t)NBUCKD * BCAPD * 4);
    int* pairB2 = (int*)alloc((size_t)NBUCKD * 8 * SCAP * 4);
    int* fillS = (int*)alloc((size_t)NBUCKD * 8 * 4);
    int* cntB = (int*)alloc((size_t)NBUCK * NBUCKD * 4);
    int* offB = (int*)alloc((size_t)NBUCK * NBUCKD * 4);
    int* fillB = (int*)alloc((size_t)NBUCKD * 4);
    ushort* Wp1 = (ushort*)alloc((size_t)2 * 4 * 16 * 512 * 2);   // K=128,M=256 hi/lo
    ushort* Wp2 = (ushort*)alloc((size_t)2 * 8 * 16 * 512 * 2);   // K=256,M=256
    ushort* Wp3 = (ushort*)alloc((size_t)2 * 8 * 8 * 512 * 2);    // K=256,M=128
    ushort* featb = (ushort*)alloc((size_t)NP * 128 * 2);   // feat*deg_out, bf16
    ushort* aggb  = (ushort*)alloc((size_t)NP * 256 * 2);   // aggregation output (reused)
    ushort* hb    = (ushort*)alloc((size_t)NP * 256 * 2);   // h*deg_out, bf16 (reused)
    ushort* yb    = (ushort*)alloc((size_t)NP * 128 * 2);   // layer-3 GEMM output
    (void)ws_size; (void)in_sizes; (void)n_in; (void)out_size;

    // graph build: src-bucket partition -> deterministic dst partition (src-ordered)
    // -> per-bucket stable split into 8 row-disjoint sub-lists -> degrees
    k_init_cur<<<2, 256, 0, stream>>>(curA);
    k_partA<<<PBLK, 256, 0, stream>>>(src, dst, curA, pairA);
    k_degout<<<NBUCK, 256, 0, stream>>>(curA, pairA, deg_out_inv);
    k_countB<<<NBUCK, 256, 0, stream>>>(curA, pairA, cntB);
    k_scanB<<<NBUCKD, 512, 0, stream>>>(cntB, offB, fillB);
    k_placeB<<<NBUCK, 256, 0, stream>>>(curA, pairA, offB, pairB);
    k_deg_in<<<NBUCKD, 256, 0, stream>>>(fillB, pairB, deg_in_inv);
    k_split8<<<NBUCKD, 512, 0, stream>>>(fillB, pairB, pairB2, fillS);

    // weights -> MFMA fragment order (hi/lo planes); feat -> bf16 with deg_out fold
    k_packAll<<<64, 256, 0, stream>>>(W1, Wp1, W2, Wp2, W3, Wp3);
    k_cvt<<<(NN * 32 + 255) / 256, 256, 0, stream>>>(feat, deg_out_inv, featb);

    // layer 1: push-agg(feat*deg_out) -> GEMM 128->256 [+b1,*deg_in,LN,PReLU,*deg_out] -> hb
    k_agg_push2<128, 0, false><<<NBUCKD, 512, 0, stream>>>(pairB2, fillS, featb, nullptr, nullptr, aggb, nullptr);
    k_gemm_mfma<128, 256, 1><<<NP / 64, 256, 0, stream>>>(aggb, Wp1, b1, deg_in_inv, deg_out_inv, g1, be1, a1, hb);

    // layer 2: push-agg(h1*deg_out) in two 128-col passes -> GEMM 256->256 [epilogue] -> hb
    k_agg_push2<256, 0, false><<<NBUCKD, 512, 0, stream>>>(pairB2, fillS, hb, nullptr, nullptr, aggb, nullptr);
    k_agg_push2<256, 128, false><<<NBUCKD, 512, 0, stream>>>(pairB2, fillS, hb, nullptr, nullptr, aggb, nullptr);
    k_gemm_mfma<256, 256, 1><<<NP / 64, 256, 0, stream>>>(aggb, Wp2, b2, deg_in_inv, deg_out_inv, g2, be2, a2, hb);

    // layer 3: GEMM (h2*deg_out)@W3 -> yb, then push-agg(yb) with (+b3)*deg_in into d_out
    k_gemm_mfma<256, 128, 0><<<NP / 128, 256, 0, stream>>>(hb, Wp3, nullptr, nullptr, nullptr, nullptr, nullptr, nullptr, yb);
    k_agg_push2<128, 0, true><<<NBUCKD, 512, 0, stream>>>(pairB2, fillS, yb, b3, deg_in_inv, nullptr, (float*)d_out);
}

// Round 4
// 680.084 us; speedup vs baseline: 8.3338x; 1.0237x over previous
//
#include <hip/hip_runtime.h>
#include <cstdint>
#include <cstddef>

static constexpr int NN = 100000;   // nodes
static constexpr int NE = 1600000;  // edges
static constexpr int NP = 100096;   // NN padded to 128-row GEMM granularity

static constexpr int NBUCK  = 391;  // src buckets (256 nodes each, src>>8)
static constexpr int BCAP   = 5120; // src bucket capacity: mean 4096 + 16 sigma
static constexpr int NBUCKD = 782;  // dst buckets (128 nodes each, dst>>7); 782*128 == NP
static constexpr int BCAPD  = 2816; // dst bucket capacity: mean 2046 + 17 sigma
static constexpr int SCAP   = 448;  // sub-list capacity: mean 256 + 12 sigma
static constexpr int PBLK   = 200;  // partition blocks
static constexpr int EPB    = 8000; // edges per partition block (PBLK*EPB == NE)

typedef __attribute__((ext_vector_type(8))) short short8;             // 8 bf16 (4 VGPRs)
typedef __attribute__((ext_vector_type(8))) unsigned short ushort8;   // 16B bf16 chunk
typedef __attribute__((ext_vector_type(4))) float f32x4;              // MFMA C/D frag

__device__ inline ushort bf16_rtn(float x) {
    uint32_t u = __float_as_uint(x);
    uint32_t r = u + 0x7fffu + ((u >> 16) & 1u);   // round-to-nearest-even
    return (ushort)(r >> 16);
}
__device__ inline float bf16_to_f(ushort u) {
    return __uint_as_float((uint32_t)u << 16);
}

// ---------------- bucket cursor init ----------------
__global__ __launch_bounds__(256) void k_init_cur(int* __restrict__ curA) {
    int b = blockIdx.x * 256 + threadIdx.x;
    if (b < NBUCK) curA[b] = b * BCAP;
}

// ---------------- phase A: partition edges by SRC bucket ----------------
// pairA = (dst<<8) | (src&255); order within bucket arbitrary (all same 256-src window)
__global__ __launch_bounds__(256) void k_partA(const int* __restrict__ src, const int* __restrict__ dst,
                                               int* __restrict__ curA, int* __restrict__ pairA) {
    __shared__ int hs[NBUCK];
    int e0 = blockIdx.x * EPB;
    for (int i = threadIdx.x; i < NBUCK; i += 256) hs[i] = 0;
    __syncthreads();
    for (int e = e0 + (int)threadIdx.x; e < e0 + EPB; e += 256)
        atomicAdd(&hs[src[e] >> 8], 1);
    __syncthreads();
    for (int i = threadIdx.x; i < NBUCK; i += 256) {
        int c = hs[i];
        hs[i] = c ? atomicAdd(&curA[i], c) : 0;
    }
    __syncthreads();
    for (int e = e0 + (int)threadIdx.x; e < e0 + EPB; e += 256) {
        int s = src[e], d = dst[e];
        int p = atomicAdd(&hs[s >> 8], 1);
        pairA[p] = (d << 8) | (s & 255);
    }
}

// ---------------- out-degree from src buckets ----------------
__global__ __launch_bounds__(256) void k_degout(const int* __restrict__ curA, const int* __restrict__ pairA,
                                                float* __restrict__ deg_out_inv) {
    __shared__ int h[256];
    int b = blockIdx.x;
    int p0 = b * BCAP;
    int n = curA[b] - p0;
    h[threadIdx.x] = 0;
    __syncthreads();
    for (int i = threadIdx.x; i < n; i += 256)
        atomicAdd(&h[pairA[p0 + i] & 255], 1);
    __syncthreads();
    int node = b * 256 + (int)threadIdx.x;
    if (node < NN)
        deg_out_inv[node] = rsqrtf(fmaxf((float)h[threadIdx.x], 1.0f));
}

// ---------------- B1: per-src-bucket histogram of dst buckets ----------------
__global__ __launch_bounds__(256) void k_countB(const int* __restrict__ curA, const int* __restrict__ pairA,
                                                int* __restrict__ cntB) {
    __shared__ int h[NBUCKD];
    int s = blockIdx.x;
    int p0 = s * BCAP;
    int n = curA[s] - p0;
    for (int i = threadIdx.x; i < NBUCKD; i += 256) h[i] = 0;
    __syncthreads();
    for (int i = threadIdx.x; i < n; i += 256)
        atomicAdd(&h[pairA[p0 + i] >> 15], 1);    // dst>>7 == pairA>>15
    __syncthreads();
    for (int i = threadIdx.x; i < NBUCKD; i += 256)
        cntB[s * NBUCKD + i] = h[i];
}

// ---------------- B2: exclusive scan over src buckets per dst bucket ----------------
__global__ __launch_bounds__(512) void k_scanB(const int* __restrict__ cntB, int* __restrict__ offB,
                                               int* __restrict__ fillB) {
    __shared__ int sd[512];
    int b = blockIdx.x;
    int t = threadIdx.x;
    int v = (t < NBUCK) ? cntB[t * NBUCKD + b] : 0;
    sd[t] = v;
    __syncthreads();
    #pragma unroll
    for (int off = 1; off < 512; off <<= 1) {
        int x = (t >= off) ? sd[t - off] : 0;
        __syncthreads();
        sd[t] += x;
        __syncthreads();
    }
    if (t < NBUCK) offB[t * NBUCKD + b] = b * BCAPD + sd[t] - v;
    if (t == NBUCK - 1) fillB[b] = sd[t];
}

// ---------------- B3: deterministic placement -> dst buckets, src-ordered ----------------
// pairB = (src<<7) | (dst&127); within dst bucket, edges ordered by src bucket.
__global__ __launch_bounds__(256) void k_placeB(const int* __restrict__ curA, const int* __restrict__ pairA,
                                                const int* __restrict__ offB, int* __restrict__ pairB) {
    __shared__ int cur[NBUCKD];
    int s = blockIdx.x;
    int p0 = s * BCAP;
    int n = curA[s] - p0;
    for (int i = threadIdx.x; i < NBUCKD; i += 256) cur[i] = offB[s * NBUCKD + i];
    __syncthreads();
    int sbase = s << 8;
    for (int i = threadIdx.x; i < n; i += 256) {
        int pk = pairA[p0 + i];
        int d = pk >> 8;
        int sfull = sbase | (pk & 255);
        int pos = atomicAdd(&cur[d >> 7], 1);
        pairB[pos] = (sfull << 7) | (d & 127);
    }
}

// ---------------- in-degree per dst bucket (covers all NP rows) ----------------
__global__ __launch_bounds__(256) void k_deg_in(const int* __restrict__ fillB, const int* __restrict__ pairB,
                                                float* __restrict__ deg_in_inv) {
    __shared__ int h[128];
    int b = blockIdx.x;
    int p0 = b * BCAPD;
    int n = fillB[b];
    if (threadIdx.x < 128) h[threadIdx.x] = 0;
    __syncthreads();
    for (int i = threadIdx.x; i < n; i += 256)
        atomicAdd(&h[pairB[p0 + i] & 127], 1);
    __syncthreads();
    if (threadIdx.x < 128) {
        int node = b * 128 + (int)threadIdx.x;          // covers exactly NP rows
        deg_in_inv[node] = rsqrtf(fmaxf((float)h[threadIdx.x], 1.0f));
    }
}

// ---------------- stable split of each dst bucket into 8 sub-lists by dl&7 ----------------
// Wave w extracts edges with (dl&7)==w, preserving src order (ballot + prefix-popc).
// Enables atomic-free LDS accumulation: wave w exclusively owns rows dl&7==w.
__global__ __launch_bounds__(512) void k_split8(const int* __restrict__ fillB, const int* __restrict__ pairB,
                                                int* __restrict__ pairB2, int* __restrict__ fillS) {
    int b = blockIdx.x;
    int w = threadIdx.x >> 6;
    int l = threadIdx.x & 63;
    int n = fillB[b];
    const int* ep = pairB + (size_t)b * BCAPD;
    int* op = pairB2 + (size_t)(b * 8 + w) * SCAP;
    int cnt = 0;
    for (int i0 = 0; i0 < n; i0 += 64) {
        int idx = i0 + l;
        int pk = (idx < n) ? ep[idx] : 0;
        bool match = (idx < n) && ((pk & 7) == w);   // pk&7 == dl&7
        unsigned long long mask = __ballot(match);
        if (match) {
            int pos = __popcll(mask & ((1ull << l) - 1ull));
            op[cnt + pos] = pk;
        }
        cnt += __popcll(mask);
    }
    if (l == 0) fillS[b * 8 + w] = cnt;
}

// ---------------- feat fp32 -> bf16 with deg_out_inv folded ----------------
__global__ __launch_bounds__(256) void k_cvt(const float* __restrict__ feat,
                                             const float* __restrict__ deg_out_inv,
                                             ushort* __restrict__ out) {
    int idx = blockIdx.x * 256 + threadIdx.x;            // one float4 per thread
    if (idx >= NN * 32) return;                          // NN*128/4
    float4 v = *(const float4*)(feat + (size_t)idx * 4);
    float w = deg_out_inv[idx >> 5];                     // (idx*4)/128
    ushort4 o;
    o.x = bf16_rtn(v.x * w);
    o.y = bf16_rtn(v.y * w);
    o.z = bf16_rtn(v.z * w);
    o.w = bf16_rtn(v.w * w);
    *(ushort4*)(out + (size_t)idx * 4) = o;
}

// ---------------- atomic-free push aggregation ----------------
// Block = one dst bucket (128 rows), 8 waves; wave w owns rows with dl&7==w and walks
// its src-sorted sub-list: per edge one coalesced 256B gather (ushort2/lane) + plain
// LDS float2 RMW (no atomics; same-row edges within a wave serialize via program order).
// All blocks sweep src space in lockstep -> gathers stay cache-resident.
template <int XSTRIDE, int COLOFF, bool FINAL>
__global__ __launch_bounds__(512) void k_agg_push2(const int* __restrict__ pairB2, const int* __restrict__ fillS,
                                                   const ushort* __restrict__ x,
                                                   const float* __restrict__ bias,
                                                   const float* __restrict__ deg_in_inv,
                                                   ushort* __restrict__ out_b, float* __restrict__ out_f) {
    __shared__ float lacc[128 * 128];
    int b = blockIdx.x;
    for (int i = threadIdx.x; i < 4096; i += 512)
        *(float4*)&lacc[i * 4] = (float4){0.f, 0.f, 0.f, 0.f};
    __syncthreads();
    int w = threadIdx.x >> 6;
    int l = threadIdx.x & 63;
    int sb = b * 8 + w;
    int m = fillS[sb];
    const int* ep = pairB2 + (size_t)sb * SCAP;
    const ushort* xb = x + COLOFF + 2 * l;
    int i = 0;
    for (; i + 8 <= m; i += 8) {
        int pk[8];
        #pragma unroll
        for (int j = 0; j < 8; ++j) pk[j] = ep[i + j];
        ushort2 v[8];
        #pragma unroll
        for (int j = 0; j < 8; ++j)
            v[j] = *(const ushort2*)(xb + (size_t)(pk[j] >> 7) * XSTRIDE);
        #pragma unroll
        for (int j = 0; j < 8; ++j) {
            int a = (pk[j] & 127) * 128 + 2 * l;
            float2 c = *(float2*)&lacc[a];
            c.x += bf16_to_f(v[j].x);
            c.y += bf16_to_f(v[j].y);
            *(float2*)&lacc[a] = c;
        }
    }
    for (; i < m; ++i) {
        int pk = ep[i];
        ushort2 vv = *(const ushort2*)(xb + (size_t)(pk >> 7) * XSTRIDE);
        int a = (pk & 127) * 128 + 2 * l;
        float2 c = *(float2*)&lacc[a];
        c.x += bf16_to_f(vv.x);
        c.y += bf16_to_f(vv.y);
        *(float2*)&lacc[a] = c;
    }
    __syncthreads();
    // writeback: wave w covers rows w*16..w*16+15; lane covers cols {2l, 2l+1}
    if constexpr (FINAL) {
        float2 bv = *(const float2*)(bias + 2 * l);
        #pragma unroll 4
        for (int rr = 0; rr < 16; ++rr) {
            int rl = w * 16 + rr;
            int node = b * 128 + rl;
            if (node < NN) {
                float dv = deg_in_inv[node];
                float2 c = *(float2*)&lacc[rl * 128 + 2 * l];
                float2 o;
                o.x = (c.x + bv.x) * dv;
                o.y = (c.y + bv.y) * dv;
                *(float2*)(out_f + (size_t)node * 128 + 2 * l) = o;
            }
        }
    } else {
        #pragma unroll 4
        for (int rr = 0; rr < 16; ++rr) {
            int rl = w * 16 + rr;
            int node = b * 128 + rl;          // < NP always; pad rows get zeros
            float2 c = *(float2*)&lacc[rl * 128 + 2 * l];
            ushort2 o;
            o.x = bf16_rtn(c.x);
            o.y = bf16_rtn(c.y);
            *(ushort2*)(out_b + (size_t)node * XSTRIDE + COLOFF + 2 * l) = o;
        }
    }
}

// ---------------- pack W[K x M] fp32 -> B-fragment-ordered bf16 hi/lo planes ----------------
template <int K, int M>
__device__ inline void packW_dev(const float* __restrict__ W, ushort* __restrict__ out, int blk) {
    constexpr int NT = M / 16, KC = K / 32;
    constexpr int WTOT = KC * NT * 512;      // elements per plane
    int idx = blk * 256 + (int)threadIdx.x;
    int lane = idx & 63;
    int tile = idx >> 6;
    int nt = tile % NT, kc = tile / NT;
    int col = nt * 16 + (lane & 15);
    int kbase = kc * 32 + (lane >> 4) * 8;
    size_t o = (size_t)tile * 512 + lane * 8;
    #pragma unroll
    for (int j = 0; j < 8; ++j) {
        float w = W[(size_t)(kbase + j) * M + col];
        uint32_t u = __float_as_uint(w);
        uint32_t hu = u & 0xffff0000u;
        float lf = w - __uint_as_float(hu);
        out[o + j] = (ushort)(u >> 16);
        out[o + WTOT + j] = (ushort)(__float_as_uint(lf) >> 16);
    }
}

__global__ __launch_bounds__(256) void k_packAll(const float* __restrict__ W1, ushort* __restrict__ o1,
                                                 const float* __restrict__ W2, ushort* __restrict__ o2,
                                                 const float* __restrict__ W3, ushort* __restrict__ o3) {
    int b = blockIdx.x;
    if (b < 16) packW_dev<128, 256>(W1, o1, b);            // 4*16 tiles
    else if (b < 48) packW_dev<256, 256>(W2, o2, b - 16);  // 8*16 tiles
    else packW_dev<256, 128>(W3, o3, b - 48);              // 8*8 tiles
}

// ---------------- bf16 MFMA GEMM v2: LDS-staged A (global_load_lds, dbuf), fused epilogue ----
// A tile per kc-step staged ONCE per block (was 4x duplicated per-wave global loads) in
// fragment-major LDS layout [buf][rf][lane][16B]: per-lane GLOBAL address carries the
// fragment swizzle, LDS stays linear (wave-uniform base + lane*16), reads are linear
// ds_read_b128 (conflict-free). Double-buffered, m97-style 2-barrier loop.
// MODE 0: out = bf16(A@W)
// MODE 1: out = bf16(prelu(LN((A@W+b)*deg_in)) * deg_out)   [requires M=256]
template <int K, int M, int MODE>
__global__ __launch_bounds__(256) void k_gemm_mfma(const ushort* __restrict__ A,
                                                   const ushort* __restrict__ Wp,
                                                   const float* __restrict__ bias,
                                                   const float* __restrict__ deg_in_inv,
                                                   const float* __restrict__ deg_out_inv,
                                                   const float* __restrict__ g,
                                                   const float* __restrict__ be,
                                                   const float* __restrict__ a,
                                                   ushort* __restrict__ out) {
    constexpr int NT = M / 16;
    constexpr int KC = K / 32;
    constexpr int WTOT = KC * NT * 512;
    constexpr int COLW = M / 64;          // waves across cols (4 for M=256, 2 for M=128)
    constexpr int ROWW = 4 / COLW;        // row groups per block
    constexpr int BROWS = 64 * ROWW;      // rows per block
    constexpr int LROW = M + 8;           // padded LDS row (ushorts)
    constexpr int NRF = BROWS / 16;       // A row-frags per kc-step (4 or 8)
    constexpr int RFW = NRF / 4;          // frags staged per wave (1 or 2)
    __shared__ ushort sbuf[BROWS * LROW]; // epilogue buffer; head doubles as A staging dbuf
    __shared__ float sredS[4][64];
    __shared__ float sredQ[4][64];
    __shared__ float smu[64];
    __shared__ float srs[64];
    static_assert(BROWS * LROW >= 2 * NRF * 512, "staging dbuf must fit in sbuf");

    int lane = threadIdx.x & 63;
    int wave = threadIdx.x >> 6;
    int cw = wave % COLW;                 // col group
    int rw = wave / COLW;                 // row group (0 when M=256)
    int m = lane & 15;
    int quad = lane >> 4;
    int rowb = blockIdx.x * BROWS + rw * 64;

    f32x4 acc[4][4];
    #pragma unroll
    for (int rf = 0; rf < 4; ++rf)
        #pragma unroll
        for (int ct = 0; ct < 4; ++ct) acc[rf][ct] = (f32x4){0.f, 0.f, 0.f, 0.f};

    // stage A frags for kc into buf: frag rf = lanes' 16B of
    // A[blockRow + rf*16 + (lane&15)][kc*32 + (lane>>4)*8 .. +8]
    const size_t arow0 = (size_t)blockIdx.x * BROWS;
    auto stage = [&](int kc, int buf) {
        #pragma unroll
        for (int s = 0; s < RFW; ++s) {
            int rf = wave * RFW + s;
            const ushort* gsrc = A + (arow0 + rf * 16 + m) * K + kc * 32 + quad * 8;
            ushort* ldst = sbuf + (size_t)(buf * NRF + rf) * 512;   // wave-uniform base
            __builtin_amdgcn_global_load_lds(
                (const __attribute__((address_space(1))) unsigned int*)gsrc,
                (__attribute__((address_space(3))) unsigned int*)ldst, 16, 0, 0);
        }
    };
    stage(0, 0);
    __syncthreads();
    for (int kc = 0; kc < KC; ++kc) {
        if (kc + 1 < KC) stage(kc + 1, (kc + 1) & 1);
        const ushort* ab = sbuf + (size_t)((kc & 1) * NRF + rw * 4) * 512 + lane * 8;
        short8 av[4];
        #pragma unroll
        for (int rf = 0; rf < 4; ++rf)
            av[rf] = *(const short8*)(ab + rf * 512);      // linear ds_read_b128
        const ushort* wb0 = Wp + ((size_t)kc * NT + cw * 4) * 512 + lane * 8;
        #pragma unroll
        for (int ct = 0; ct < 4; ++ct) {
            short8 bh = *(const short8*)(wb0 + ct * 512);
            short8 bl = *(const short8*)(wb0 + WTOT + ct * 512);
            #pragma unroll
            for (int rf = 0; rf < 4; ++rf) {
                acc[rf][ct] = __builtin_amdgcn_mfma_f32_16x16x32_bf16(av[rf], bh, acc[rf][ct], 0, 0, 0);
                acc[rf][ct] = __builtin_amdgcn_mfma_f32_16x16x32_bf16(av[rf], bl, acc[rf][ct], 0, 0, 0);
            }
        }
        __syncthreads();   // drains vmcnt: next buf staged; all waves done reading this buf
    }
    // acc[rf][ct][r] holds row_local = rw*64 + rf*16 + quad*4 + r, col = cw*64 + ct*16 + m
    if constexpr (MODE == 1) {
        float bia[4];
        #pragma unroll
        for (int ct = 0; ct < 4; ++ct) bia[ct] = bias[cw * 64 + ct * 16 + m];
        float din[4][4], fold[4][4];
        #pragma unroll
        for (int rf = 0; rf < 4; ++rf)
            #pragma unroll
            for (int r = 0; r < 4; ++r) {
                int row = rowb + rf * 16 + quad * 4 + r;
                din[rf][r] = deg_in_inv[row];
                fold[rf][r] = deg_out_inv[row];
            }
        float s[4][4], q[4][4];
        #pragma unroll
        for (int rf = 0; rf < 4; ++rf)
            #pragma unroll
            for (int r = 0; r < 4; ++r) { s[rf][r] = 0.f; q[rf][r] = 0.f; }
        #pragma unroll
        for (int rf = 0; rf < 4; ++rf)
            #pragma unroll
            for (int ct = 0; ct < 4; ++ct)
                #pragma unroll
                for (int r = 0; r < 4; ++r) {
                    float v = (acc[rf][ct][r] + bia[ct]) * din[rf][r];
                    acc[rf][ct][r] = v;
                    s[rf][r] += v;
                    q[rf][r] += v * v;
                }
        #pragma unroll
        for (int w = 1; w < 16; w <<= 1)
            #pragma unroll
            for (int rf = 0; rf < 4; ++rf)
                #pragma unroll
                for (int r = 0; r < 4; ++r) {
                    s[rf][r] += __shfl_xor(s[rf][r], w);
                    q[rf][r] += __shfl_xor(q[rf][r], w);
                }
        if (m == 0) {
            #pragma unroll
            for (int rf = 0; rf < 4; ++rf)
                #pragma unroll
                for (int r = 0; r < 4; ++r) {
                    int rl = rf * 16 + quad * 4 + r;
                    sredS[wave][rl] = s[rf][r];
                    sredQ[wave][rl] = q[rf][r];
                }
        }
        __syncthreads();
        if (threadIdx.x < 64) {
            int rl = threadIdx.x;
            float st = sredS[0][rl] + sredS[1][rl] + sredS[2][rl] + sredS[3][rl];
            float qt = sredQ[0][rl] + sredQ[1][rl] + sredQ[2][rl] + sredQ[3][rl];
            float mu = st * (1.0f / M);
            float var = qt * (1.0f / M) - mu * mu;
            smu[rl] = mu;
            srs[rl] = rsqrtf(var + 1e-5f);
        }
        __syncthreads();
        float alpha = a[0];
        float gv[4], bev[4];
        #pragma unroll
        for (int ct = 0; ct < 4; ++ct) {
            gv[ct] = g[cw * 64 + ct * 16 + m];
            bev[ct] = be[cw * 64 + ct * 16 + m];
        }
        #pragma unroll
        for (int rf = 0; rf < 4; ++rf)
            #pragma unroll
            for (int r = 0; r < 4; ++r) {
                int rl = rf * 16 + quad * 4 + r;
                float mu = smu[rl];
                float rs = srs[rl];
                float fo = fold[rf][r];
                #pragma unroll
                for (int ct = 0; ct < 4; ++ct) {
                    float v = gv[ct] * (acc[rf][ct][r] - mu) * rs + bev[ct];
                    v = (v >= 0.0f) ? v : alpha * v;
                    v *= fo;
                    sbuf[rl * LROW + cw * 64 + ct * 16 + m] = bf16_rtn(v);
                }
            }
    } else {
        #pragma unroll
        for (int rf = 0; rf < 4; ++rf)
            #pragma unroll
            for (int ct = 0; ct < 4; ++ct)
                #pragma unroll
                for (int r = 0; r < 4; ++r)
                    sbuf[(rw * 64 + rf * 16 + quad * 4 + r) * LROW + cw * 64 + ct * 16 + m] =
                        bf16_rtn(acc[rf][ct][r]);
    }
    __syncthreads();
    constexpr int CNT = BROWS * M / 256;        // 64 both cases
    int trow = ((int)threadIdx.x * CNT) / M;
    int tcol = ((int)threadIdx.x * CNT) % M;
    const ushort* rsrc = sbuf + trow * LROW + tcol;
    ushort* gdst = out + (size_t)(blockIdx.x * BROWS + trow) * M + tcol;
    #pragma unroll
    for (int j = 0; j < CNT / 8; ++j) {
        ushort8 v = *(const ushort8*)(rsrc + j * 8);
        *(ushort8*)(gdst + j * 8) = v;
    }
}

extern "C" void kernel_launch(void* const* d_in, const int* in_sizes, int n_in,
                              void* d_out, int out_size, void* d_ws, size_t ws_size,
                              hipStream_t stream) {
    const float* feat = (const float*)d_in[0];
    const float* W1 = (const float*)d_in[1];
    const float* b1 = (const float*)d_in[2];
    const float* g1 = (const float*)d_in[3];
    const float* be1 = (const float*)d_in[4];
    const float* a1 = (const float*)d_in[5];
    const float* W2 = (const float*)d_in[6];
    const float* b2 = (const float*)d_in[7];
    const float* g2 = (const float*)d_in[8];
    const float* be2 = (const float*)d_in[9];
    const float* a2 = (const float*)d_in[10];
    const float* W3 = (const float*)d_in[11];
    const float* b3 = (const float*)d_in[12];
    const int* src = (const int*)d_in[13];
    const int* dst = (const int*)d_in[14];

    char* ws = (char*)d_ws;
    size_t off = 0;
    auto alloc = [&](size_t bytes) -> void* {
        off = (off + 511) & ~(size_t)511;
        void* p = ws + off;
        off += bytes;
        return p;
    };
    int* curA = (int*)alloc((size_t)NBUCK * 4);
    float* deg_out_inv = (float*)alloc((size_t)NP * 4);
    float* deg_in_inv = (float*)alloc((size_t)NP * 4);
    int* pairA = (int*)alloc((size_t)NBUCK * BCAP * 4);
    int* pairB = (int*)alloc((size_t)NBUCKD * BCAPD * 4);
    int* pairB2 = (int*)alloc((size_t)NBUCKD * 8 * SCAP * 4);
    int* fillS = (int*)alloc((size_t)NBUCKD * 8 * 4);
    int* cntB = (int*)alloc((size_t)NBUCK * NBUCKD * 4);
    int* offB = (int*)alloc((size_t)NBUCK * NBUCKD * 4);
    int* fillB = (int*)alloc((size_t)NBUCKD * 4);
    ushort* Wp1 = (ushort*)alloc((size_t)2 * 4 * 16 * 512 * 2);   // K=128,M=256 hi/lo
    ushort* Wp2 = (ushort*)alloc((size_t)2 * 8 * 16 * 512 * 2);   // K=256,M=256
    ushort* Wp3 = (ushort*)alloc((size_t)2 * 8 * 8 * 512 * 2);    // K=256,M=128
    ushort* featb = (ushort*)alloc((size_t)NP * 128 * 2);   // feat*deg_out, bf16
    ushort* aggb  = (ushort*)alloc((size_t)NP * 256 * 2);   // aggregation output (reused)
    ushort* hb    = (ushort*)alloc((size_t)NP * 256 * 2);   // h*deg_out, bf16 (reused)
    ushort* yb    = (ushort*)alloc((size_t)NP * 128 * 2);   // layer-3 GEMM output
    (void)ws_size; (void)in_sizes; (void)n_in; (void)out_size;

    // graph build: src-bucket partition -> deterministic dst partition (src-ordered)
    // -> per-bucket stable split into 8 row-disjoint sub-lists -> degrees
    k_init_cur<<<2, 256, 0, stream>>>(curA);
    k_partA<<<PBLK, 256, 0, stream>>>(src, dst, curA, pairA);
    k_degout<<<NBUCK, 256, 0, stream>>>(curA, pairA, deg_out_inv);
    k_countB<<<NBUCK, 256, 0, stream>>>(curA, pairA, cntB);
    k_scanB<<<NBUCKD, 512, 0, stream>>>(cntB, offB, fillB);
    k_placeB<<<NBUCK, 256, 0, stream>>>(curA, pairA, offB, pairB);
    k_deg_in<<<NBUCKD, 256, 0, stream>>>(fillB, pairB, deg_in_inv);
    k_split8<<<NBUCKD, 512, 0, stream>>>(fillB, pairB, pairB2, fillS);

    // weights -> MFMA fragment order (hi/lo planes); feat -> bf16 with deg_out fold
    k_packAll<<<64, 256, 0, stream>>>(W1, Wp1, W2, Wp2, W3, Wp3);
    k_cvt<<<(NN * 32 + 255) / 256, 256, 0, stream>>>(feat, deg_out_inv, featb);

    // layer 1: push-agg(feat*deg_out) -> GEMM 128->256 [+b1,*deg_in,LN,PReLU,*deg_out] -> hb
    k_agg_push2<128, 0, false><<<NBUCKD, 512, 0, stream>>>(pairB2, fillS, featb, nullptr, nullptr, aggb, nullptr);
    k_gemm_mfma<128, 256, 1><<<NP / 64, 256, 0, stream>>>(aggb, Wp1, b1, deg_in_inv, deg_out_inv, g1, be1, a1, hb);

    // layer 2: push-agg(h1*deg_out) in two 128-col passes -> GEMM 256->256 [epilogue] -> hb
    k_agg_push2<256, 0, false><<<NBUCKD, 512, 0, stream>>>(pairB2, fillS, hb, nullptr, nullptr, aggb, nullptr);
    k_agg_push2<256, 128, false><<<NBUCKD, 512, 0, stream>>>(pairB2, fillS, hb, nullptr, nullptr, aggb, nullptr);
    k_gemm_mfma<256, 256, 1><<<NP / 64, 256, 0, stream>>>(aggb, Wp2, b2, deg_in_inv, deg_out_inv, g2, be2, a2, hb);

    // layer 3: GEMM (h2*deg_out)@W3 -> yb, then push-agg(yb) with (+b3)*deg_in into d_out
    k_gemm_mfma<256, 128, 0><<<NP / 128, 256, 0, stream>>>(hb, Wp3, nullptr, nullptr, nullptr, nullptr, nullptr, nullptr, yb);
    k_agg_push2<128, 0, true><<<NBUCKD, 512, 0, stream>>>(pairB2, fillS, yb, b3, deg_in_inv, nullptr, (float*)d_out);
}

// Round 5
// 638.372 us; speedup vs baseline: 8.8784x; 1.0653x over previous
//
#include <hip/hip_runtime.h>
#include <cstdint>
#include <cstddef>

static constexpr int NN = 100000;   // nodes
static constexpr int NE = 1600000;  // edges
static constexpr int NP = 100096;   // NN padded to 128-row GEMM granularity

static constexpr int NBUCK  = 391;  // src buckets (256 nodes each, src>>8)
static constexpr int BCAP   = 5120; // src bucket capacity: mean 4096 + 16 sigma
static constexpr int NBUCKD = 782;  // dst buckets (128 nodes each, dst>>7); 782*128 == NP
static constexpr int BCAPD  = 2816; // dst bucket capacity: mean 2046 + 17 sigma
static constexpr int SCAP   = 128;  // 32-way sub-list capacity: mean 64 + 8 sigma
static constexpr int PBLK   = 200;  // partition blocks
static constexpr int EPB    = 8000; // edges per partition block (PBLK*EPB == NE)

typedef __attribute__((ext_vector_type(8))) short short8;             // 8 bf16 (4 VGPRs)
typedef __attribute__((ext_vector_type(8))) unsigned short ushort8;   // 16B bf16 chunk
typedef __attribute__((ext_vector_type(4))) float f32x4;              // MFMA C/D frag

__device__ inline ushort bf16_rtn(float x) {
    uint32_t u = __float_as_uint(x);
    uint32_t r = u + 0x7fffu + ((u >> 16) & 1u);   // round-to-nearest-even
    return (ushort)(r >> 16);
}
__device__ inline float bf16_to_f(ushort u) {
    return __uint_as_float((uint32_t)u << 16);
}

// ---------------- bucket cursor init ----------------
__global__ __launch_bounds__(256) void k_init_cur(int* __restrict__ curA) {
    int b = blockIdx.x * 256 + threadIdx.x;
    if (b < NBUCK) curA[b] = b * BCAP;
}

// ---------------- phase A: partition edges by SRC bucket ----------------
// pairA = (dst<<8) | (src&255); order within bucket arbitrary (all same 256-src window)
__global__ __launch_bounds__(256) void k_partA(const int* __restrict__ src, const int* __restrict__ dst,
                                               int* __restrict__ curA, int* __restrict__ pairA) {
    __shared__ int hs[NBUCK];
    int e0 = blockIdx.x * EPB;
    for (int i = threadIdx.x; i < NBUCK; i += 256) hs[i] = 0;
    __syncthreads();
    for (int e = e0 + (int)threadIdx.x; e < e0 + EPB; e += 256)
        atomicAdd(&hs[src[e] >> 8], 1);
    __syncthreads();
    for (int i = threadIdx.x; i < NBUCK; i += 256) {
        int c = hs[i];
        hs[i] = c ? atomicAdd(&curA[i], c) : 0;
    }
    __syncthreads();
    for (int e = e0 + (int)threadIdx.x; e < e0 + EPB; e += 256) {
        int s = src[e], d = dst[e];
        int p = atomicAdd(&hs[s >> 8], 1);
        pairA[p] = (d << 8) | (s & 255);
    }
}

// ---------------- out-degree from src buckets ----------------
__global__ __launch_bounds__(256) void k_degout(const int* __restrict__ curA, const int* __restrict__ pairA,
                                                float* __restrict__ deg_out_inv) {
    __shared__ int h[256];
    int b = blockIdx.x;
    int p0 = b * BCAP;
    int n = curA[b] - p0;
    h[threadIdx.x] = 0;
    __syncthreads();
    for (int i = threadIdx.x; i < n; i += 256)
        atomicAdd(&h[pairA[p0 + i] & 255], 1);
    __syncthreads();
    int node = b * 256 + (int)threadIdx.x;
    if (node < NN)
        deg_out_inv[node] = rsqrtf(fmaxf((float)h[threadIdx.x], 1.0f));
}

// ---------------- B1: per-src-bucket histogram of dst buckets ----------------
__global__ __launch_bounds__(256) void k_countB(const int* __restrict__ curA, const int* __restrict__ pairA,
                                                int* __restrict__ cntB) {
    __shared__ int h[NBUCKD];
    int s = blockIdx.x;
    int p0 = s * BCAP;
    int n = curA[s] - p0;
    for (int i = threadIdx.x; i < NBUCKD; i += 256) h[i] = 0;
    __syncthreads();
    for (int i = threadIdx.x; i < n; i += 256)
        atomicAdd(&h[pairA[p0 + i] >> 15], 1);    // dst>>7 == pairA>>15
    __syncthreads();
    for (int i = threadIdx.x; i < NBUCKD; i += 256)
        cntB[s * NBUCKD + i] = h[i];
}

// ---------------- B2: exclusive scan over src buckets per dst bucket ----------------
__global__ __launch_bounds__(512) void k_scanB(const int* __restrict__ cntB, int* __restrict__ offB,
                                               int* __restrict__ fillB) {
    __shared__ int sd[512];
    int b = blockIdx.x;
    int t = threadIdx.x;
    int v = (t < NBUCK) ? cntB[t * NBUCKD + b] : 0;
    sd[t] = v;
    __syncthreads();
    #pragma unroll
    for (int off = 1; off < 512; off <<= 1) {
        int x = (t >= off) ? sd[t - off] : 0;
        __syncthreads();
        sd[t] += x;
        __syncthreads();
    }
    if (t < NBUCK) offB[t * NBUCKD + b] = b * BCAPD + sd[t] - v;
    if (t == NBUCK - 1) fillB[b] = sd[t];
}

// ---------------- B3: deterministic placement -> dst buckets, src-ordered ----------------
// pairB = (src<<7) | (dst&127); within dst bucket, edges ordered by src bucket.
__global__ __launch_bounds__(256) void k_placeB(const int* __restrict__ curA, const int* __restrict__ pairA,
                                                const int* __restrict__ offB, int* __restrict__ pairB) {
    __shared__ int cur[NBUCKD];
    int s = blockIdx.x;
    int p0 = s * BCAP;
    int n = curA[s] - p0;
    for (int i = threadIdx.x; i < NBUCKD; i += 256) cur[i] = offB[s * NBUCKD + i];
    __syncthreads();
    int sbase = s << 8;
    for (int i = threadIdx.x; i < n; i += 256) {
        int pk = pairA[p0 + i];
        int d = pk >> 8;
        int sfull = sbase | (pk & 255);
        int pos = atomicAdd(&cur[d >> 7], 1);
        pairB[pos] = (sfull << 7) | (d & 127);
    }
}

// ---------------- in-degree per dst bucket (covers all NP rows) ----------------
__global__ __launch_bounds__(256) void k_deg_in(const int* __restrict__ fillB, const int* __restrict__ pairB,
                                                float* __restrict__ deg_in_inv) {
    __shared__ int h[128];
    int b = blockIdx.x;
    int p0 = b * BCAPD;
    int n = fillB[b];
    if (threadIdx.x < 128) h[threadIdx.x] = 0;
    __syncthreads();
    for (int i = threadIdx.x; i < n; i += 256)
        atomicAdd(&h[pairB[p0 + i] & 127], 1);
    __syncthreads();
    if (threadIdx.x < 128) {
        int node = b * 128 + (int)threadIdx.x;          // covers exactly NP rows
        deg_in_inv[node] = rsqrtf(fmaxf((float)h[threadIdx.x], 1.0f));
    }
}

// ---------------- stable split of each dst bucket into 32 sub-lists by dl&31 ----------------
// Bucket staged in LDS; wave w extracts sub-lists h = w + 8r (r=0..3) via ballot + prefix
// popc (stable -> src order preserved). Half-wave h of the agg kernel then exclusively
// owns rows with dl&31==h -> atomic-free LDS accumulation.
__global__ __launch_bounds__(512) void k_split32(const int* __restrict__ fillB, const int* __restrict__ pairB,
                                                 int* __restrict__ pairB2, int* __restrict__ fillS) {
    __shared__ int se[BCAPD];
    int b = blockIdx.x;
    int n = fillB[b];
    const int* ep = pairB + (size_t)b * BCAPD;
    for (int i = threadIdx.x; i < n; i += 512) se[i] = ep[i];
    __syncthreads();
    int w = threadIdx.x >> 6;
    int l = threadIdx.x & 63;
    for (int r = 0; r < 4; ++r) {
        int h = w + 8 * r;
        int* op = pairB2 + (size_t)(b * 32 + h) * SCAP;
        int cnt = 0;
        for (int i0 = 0; i0 < n; i0 += 64) {
            int idx = i0 + l;
            int pk = (idx < n) ? se[idx] : 0;
            bool match = (idx < n) && ((pk & 31) == h);   // pk&31 == dl&31
            unsigned long long mask = __ballot(match);
            if (match) {
                int pos = __popcll(mask & ((1ull << l) - 1ull));
                op[cnt + pos] = pk;
            }
            cnt += __popcll(mask);
        }
        if (l == 0) fillS[b * 32 + h] = cnt;
    }
}

// ---------------- feat fp32 -> bf16 with deg_out_inv folded ----------------
__global__ __launch_bounds__(256) void k_cvt(const float* __restrict__ feat,
                                             const float* __restrict__ deg_out_inv,
                                             ushort* __restrict__ out) {
    int idx = blockIdx.x * 256 + threadIdx.x;            // one float4 per thread
    if (idx >= NN * 32) return;                          // NN*128/4
    float4 v = *(const float4*)(feat + (size_t)idx * 4);
    float w = deg_out_inv[idx >> 5];                     // (idx*4)/128
    ushort4 o;
    o.x = bf16_rtn(v.x * w);
    o.y = bf16_rtn(v.y * w);
    o.z = bf16_rtn(v.z * w);
    o.w = bf16_rtn(v.w * w);
    *(ushort4*)(out + (size_t)idx * 4) = o;
}

// ---------------- atomic-free push aggregation, half-wave per edge ----------------
// Block = one dst bucket (128 rows), 1024 threads = 32 half-waves; half-wave h owns rows
// with dl&31==h and walks its src-sorted sub-list. Per edge: one ushort4/lane gather
// (256B per half-wave) + one float4 LDS RMW (ds_read_b128/ds_write_b128), no atomics.
// Two edges ride on every wave instruction (two halves, disjoint row sets).
// All blocks sweep src space in lockstep -> gathers stay cache-resident.
template <int XSTRIDE, int COLOFF, bool FINAL>
__global__ __launch_bounds__(1024) void k_agg_push3(const int* __restrict__ pairB2, const int* __restrict__ fillS,
                                                    const ushort* __restrict__ x,
                                                    const float* __restrict__ bias,
                                                    const float* __restrict__ deg_in_inv,
                                                    ushort* __restrict__ out_b, float* __restrict__ out_f) {
    __shared__ float lacc[128 * 128];
    int b = blockIdx.x;
    for (int i = threadIdx.x; i < 4096; i += 1024)
        *(float4*)&lacc[i * 4] = (float4){0.f, 0.f, 0.f, 0.f};
    __syncthreads();
    int h = threadIdx.x >> 5;        // half-wave 0..31 (owns rows dl&31==h)
    int l5 = threadIdx.x & 31;
    int sb = b * 32 + h;
    int m = fillS[sb];
    const int* ep = pairB2 + (size_t)sb * SCAP;
    const ushort* xb = x + COLOFF + l5 * 4;
    for (int i0 = 0; i0 < m; i0 += 4) {              // non-uniform bound: exec-masked
        int4 pks = *(const int4*)(ep + i0);          // 4 edges, broadcast within half
        int pk[4] = {pks.x, pks.y, pks.z, pks.w};
        ushort4 v[4];
        float wt[4];
        #pragma unroll
        for (int j = 0; j < 4; ++j) {
            bool ok = (i0 + j < m);
            wt[j] = ok ? 1.0f : 0.0f;
            pk[j] = ok ? pk[j] : pk[0];              // pk[0] valid & row owned by this half
            v[j] = *(const ushort4*)(xb + (size_t)(pk[j] >> 7) * XSTRIDE);
        }
        #pragma unroll
        for (int j = 0; j < 4; ++j) {
            int a = (pk[j] & 127) * 128 + l5 * 4;
            float4 c = *(float4*)&lacc[a];
            c.x += wt[j] * bf16_to_f(v[j].x);
            c.y += wt[j] * bf16_to_f(v[j].y);
            c.z += wt[j] * bf16_to_f(v[j].z);
            c.w += wt[j] * bf16_to_f(v[j].w);
            *(float4*)&lacc[a] = c;
        }
    }
    __syncthreads();
    // writeback: thread covers 16 consecutive cols of one row
    int row = threadIdx.x >> 3;
    int cg = threadIdx.x & 7;
    int node = b * 128 + row;
    const float* lp = &lacc[row * 128 + cg * 16];
    if constexpr (FINAL) {
        if (node < NN) {
            float dv = deg_in_inv[node];
            float* op = out_f + (size_t)node * 128 + cg * 16;
            #pragma unroll
            for (int gq = 0; gq < 4; ++gq) {
                float4 c = *(const float4*)(lp + gq * 4);
                float4 bv = *(const float4*)(bias + cg * 16 + gq * 4);
                float4 o;
                o.x = (c.x + bv.x) * dv;
                o.y = (c.y + bv.y) * dv;
                o.z = (c.z + bv.z) * dv;
                o.w = (c.w + bv.w) * dv;
                *(float4*)(op + gq * 4) = o;
            }
        }
    } else {
        ushort8 u0, u1;
        #pragma unroll
        for (int k = 0; k < 8; ++k) {
            u0[k] = bf16_rtn(lp[k]);
            u1[k] = bf16_rtn(lp[8 + k]);
        }
        ushort* op = out_b + (size_t)node * XSTRIDE + COLOFF + cg * 16;
        *(ushort8*)op = u0;
        *(ushort8*)(op + 8) = u1;
    }
}

// ---------------- pack W[K x M] fp32 -> B-fragment-ordered bf16 hi/lo planes ----------------
template <int K, int M>
__device__ inline void packW_dev(const float* __restrict__ W, ushort* __restrict__ out, int blk) {
    constexpr int NT = M / 16, KC = K / 32;
    constexpr int WTOT = KC * NT * 512;      // elements per plane
    int idx = blk * 256 + (int)threadIdx.x;
    int lane = idx & 63;
    int tile = idx >> 6;
    int nt = tile % NT, kc = tile / NT;
    int col = nt * 16 + (lane & 15);
    int kbase = kc * 32 + (lane >> 4) * 8;
    size_t o = (size_t)tile * 512 + lane * 8;
    #pragma unroll
    for (int j = 0; j < 8; ++j) {
        float w = W[(size_t)(kbase + j) * M + col];
        uint32_t u = __float_as_uint(w);
        uint32_t hu = u & 0xffff0000u;
        float lf = w - __uint_as_float(hu);
        out[o + j] = (ushort)(u >> 16);
        out[o + WTOT + j] = (ushort)(__float_as_uint(lf) >> 16);
    }
}

__global__ __launch_bounds__(256) void k_packAll(const float* __restrict__ W1, ushort* __restrict__ o1,
                                                 const float* __restrict__ W2, ushort* __restrict__ o2,
                                                 const float* __restrict__ W3, ushort* __restrict__ o3) {
    int b = blockIdx.x;
    if (b < 16) packW_dev<128, 256>(W1, o1, b);            // 4*16 tiles
    else if (b < 48) packW_dev<256, 256>(W2, o2, b - 16);  // 8*16 tiles
    else packW_dev<256, 128>(W3, o3, b - 48);              // 8*8 tiles
}

// ---------------- bf16 MFMA GEMM v2: LDS-staged A (global_load_lds, dbuf), fused epilogue ----
// A tile per kc-step staged ONCE per block in fragment-major LDS layout [buf][rf][lane][16B]:
// per-lane GLOBAL address carries the fragment swizzle, LDS stays linear, reads are linear
// ds_read_b128 (conflict-free). Double-buffered, m97-style 2-barrier loop.
// MODE 0: out = bf16(A@W)
// MODE 1: out = bf16(prelu(LN((A@W+b)*deg_in)) * deg_out)   [requires M=256]
template <int K, int M, int MODE>
__global__ __launch_bounds__(256) void k_gemm_mfma(const ushort* __restrict__ A,
                                                   const ushort* __restrict__ Wp,
                                                   const float* __restrict__ bias,
                                                   const float* __restrict__ deg_in_inv,
                                                   const float* __restrict__ deg_out_inv,
                                                   const float* __restrict__ g,
                                                   const float* __restrict__ be,
                                                   const float* __restrict__ a,
                                                   ushort* __restrict__ out) {
    constexpr int NT = M / 16;
    constexpr int KC = K / 32;
    constexpr int WTOT = KC * NT * 512;
    constexpr int COLW = M / 64;          // waves across cols (4 for M=256, 2 for M=128)
    constexpr int ROWW = 4 / COLW;        // row groups per block
    constexpr int BROWS = 64 * ROWW;      // rows per block
    constexpr int LROW = M + 8;           // padded LDS row (ushorts)
    constexpr int NRF = BROWS / 16;       // A row-frags per kc-step (4 or 8)
    constexpr int RFW = NRF / 4;          // frags staged per wave (1 or 2)
    __shared__ ushort sbuf[BROWS * LROW]; // epilogue buffer; head doubles as A staging dbuf
    __shared__ float sredS[4][64];
    __shared__ float sredQ[4][64];
    __shared__ float smu[64];
    __shared__ float srs[64];
    static_assert(BROWS * LROW >= 2 * NRF * 512, "staging dbuf must fit in sbuf");

    int lane = threadIdx.x & 63;
    int wave = threadIdx.x >> 6;
    int cw = wave % COLW;                 // col group
    int rw = wave / COLW;                 // row group (0 when M=256)
    int m = lane & 15;
    int quad = lane >> 4;
    int rowb = blockIdx.x * BROWS + rw * 64;

    f32x4 acc[4][4];
    #pragma unroll
    for (int rf = 0; rf < 4; ++rf)
        #pragma unroll
        for (int ct = 0; ct < 4; ++ct) acc[rf][ct] = (f32x4){0.f, 0.f, 0.f, 0.f};

    const size_t arow0 = (size_t)blockIdx.x * BROWS;
    auto stage = [&](int kc, int buf) {
        #pragma unroll
        for (int s = 0; s < RFW; ++s) {
            int rf = wave * RFW + s;
            const ushort* gsrc = A + (arow0 + rf * 16 + m) * K + kc * 32 + quad * 8;
            ushort* ldst = sbuf + (size_t)(buf * NRF + rf) * 512;   // wave-uniform base
            __builtin_amdgcn_global_load_lds(
                (const __attribute__((address_space(1))) unsigned int*)gsrc,
                (__attribute__((address_space(3))) unsigned int*)ldst, 16, 0, 0);
        }
    };
    stage(0, 0);
    __syncthreads();
    for (int kc = 0; kc < KC; ++kc) {
        if (kc + 1 < KC) stage(kc + 1, (kc + 1) & 1);
        const ushort* ab = sbuf + (size_t)((kc & 1) * NRF + rw * 4) * 512 + lane * 8;
        short8 av[4];
        #pragma unroll
        for (int rf = 0; rf < 4; ++rf)
            av[rf] = *(const short8*)(ab + rf * 512);      // linear ds_read_b128
        const ushort* wb0 = Wp + ((size_t)kc * NT + cw * 4) * 512 + lane * 8;
        #pragma unroll
        for (int ct = 0; ct < 4; ++ct) {
            short8 bh = *(const short8*)(wb0 + ct * 512);
            short8 bl = *(const short8*)(wb0 + WTOT + ct * 512);
            #pragma unroll
            for (int rf = 0; rf < 4; ++rf) {
                acc[rf][ct] = __builtin_amdgcn_mfma_f32_16x16x32_bf16(av[rf], bh, acc[rf][ct], 0, 0, 0);
                acc[rf][ct] = __builtin_amdgcn_mfma_f32_16x16x32_bf16(av[rf], bl, acc[rf][ct], 0, 0, 0);
            }
        }
        __syncthreads();   // drains vmcnt: next buf staged; all waves done reading this buf
    }
    // acc[rf][ct][r] holds row_local = rw*64 + rf*16 + quad*4 + r, col = cw*64 + ct*16 + m
    if constexpr (MODE == 1) {
        float bia[4];
        #pragma unroll
        for (int ct = 0; ct < 4; ++ct) bia[ct] = bias[cw * 64 + ct * 16 + m];
        float din[4][4], fold[4][4];
        #pragma unroll
        for (int rf = 0; rf < 4; ++rf)
            #pragma unroll
            for (int r = 0; r < 4; ++r) {
                int row = rowb + rf * 16 + quad * 4 + r;
                din[rf][r] = deg_in_inv[row];
                fold[rf][r] = deg_out_inv[row];
            }
        float s[4][4], q[4][4];
        #pragma unroll
        for (int rf = 0; rf < 4; ++rf)
            #pragma unroll
            for (int r = 0; r < 4; ++r) { s[rf][r] = 0.f; q[rf][r] = 0.f; }
        #pragma unroll
        for (int rf = 0; rf < 4; ++rf)
            #pragma unroll
            for (int ct = 0; ct < 4; ++ct)
                #pragma unroll
                for (int r = 0; r < 4; ++r) {
                    float v = (acc[rf][ct][r] + bia[ct]) * din[rf][r];
                    acc[rf][ct][r] = v;
                    s[rf][r] += v;
                    q[rf][r] += v * v;
                }
        #pragma unroll
        for (int w = 1; w < 16; w <<= 1)
            #pragma unroll
            for (int rf = 0; rf < 4; ++rf)
                #pragma unroll
                for (int r = 0; r < 4; ++r) {
                    s[rf][r] += __shfl_xor(s[rf][r], w);
                    q[rf][r] += __shfl_xor(q[rf][r], w);
                }
        if (m == 0) {
            #pragma unroll
            for (int rf = 0; rf < 4; ++rf)
                #pragma unroll
                for (int r = 0; r < 4; ++r) {
                    int rl = rf * 16 + quad * 4 + r;
                    sredS[wave][rl] = s[rf][r];
                    sredQ[wave][rl] = q[rf][r];
                }
        }
        __syncthreads();
        if (threadIdx.x < 64) {
            int rl = threadIdx.x;
            float st = sredS[0][rl] + sredS[1][rl] + sredS[2][rl] + sredS[3][rl];
            float qt = sredQ[0][rl] + sredQ[1][rl] + sredQ[2][rl] + sredQ[3][rl];
            float mu = st * (1.0f / M);
            float var = qt * (1.0f / M) - mu * mu;
            smu[rl] = mu;
            srs[rl] = rsqrtf(var + 1e-5f);
        }
        __syncthreads();
        float alpha = a[0];
        float gv[4], bev[4];
        #pragma unroll
        for (int ct = 0; ct < 4; ++ct) {
            gv[ct] = g[cw * 64 + ct * 16 + m];
            bev[ct] = be[cw * 64 + ct * 16 + m];
        }
        #pragma unroll
        for (int rf = 0; rf < 4; ++rf)
            #pragma unroll
            for (int r = 0; r < 4; ++r) {
                int rl = rf * 16 + quad * 4 + r;
                float mu = smu[rl];
                float rs = srs[rl];
                float fo = fold[rf][r];
                #pragma unroll
                for (int ct = 0; ct < 4; ++ct) {
                    float v = gv[ct] * (acc[rf][ct][r] - mu) * rs + bev[ct];
                    v = (v >= 0.0f) ? v : alpha * v;
                    v *= fo;
                    sbuf[rl * LROW + cw * 64 + ct * 16 + m] = bf16_rtn(v);
                }
            }
    } else {
        #pragma unroll
        for (int rf = 0; rf < 4; ++rf)
            #pragma unroll
            for (int ct = 0; ct < 4; ++ct)
                #pragma unroll
                for (int r = 0; r < 4; ++r)
                    sbuf[(rw * 64 + rf * 16 + quad * 4 + r) * LROW + cw * 64 + ct * 16 + m] =
                        bf16_rtn(acc[rf][ct][r]);
    }
    __syncthreads();
    constexpr int CNT = BROWS * M / 256;        // 64 both cases
    int trow = ((int)threadIdx.x * CNT) / M;
    int tcol = ((int)threadIdx.x * CNT) % M;
    const ushort* rsrc = sbuf + trow * LROW + tcol;
    ushort* gdst = out + (size_t)(blockIdx.x * BROWS + trow) * M + tcol;
    #pragma unroll
    for (int j = 0; j < CNT / 8; ++j) {
        ushort8 v = *(const ushort8*)(rsrc + j * 8);
        *(ushort8*)(gdst + j * 8) = v;
    }
}

extern "C" void kernel_launch(void* const* d_in, const int* in_sizes, int n_in,
                              void* d_out, int out_size, void* d_ws, size_t ws_size,
                              hipStream_t stream) {
    const float* feat = (const float*)d_in[0];
    const float* W1 = (const float*)d_in[1];
    const float* b1 = (const float*)d_in[2];
    const float* g1 = (const float*)d_in[3];
    const float* be1 = (const float*)d_in[4];
    const float* a1 = (const float*)d_in[5];
    const float* W2 = (const float*)d_in[6];
    const float* b2 = (const float*)d_in[7];
    const float* g2 = (const float*)d_in[8];
    const float* be2 = (const float*)d_in[9];
    const float* a2 = (const float*)d_in[10];
    const float* W3 = (const float*)d_in[11];
    const float* b3 = (const float*)d_in[12];
    const int* src = (const int*)d_in[13];
    const int* dst = (const int*)d_in[14];

    char* ws = (char*)d_ws;
    size_t off = 0;
    auto alloc = [&](size_t bytes) -> void* {
        off = (off + 511) & ~(size_t)511;
        void* p = ws + off;
        off += bytes;
        return p;
    };
    int* curA = (int*)alloc((size_t)NBUCK * 4);
    float* deg_out_inv = (float*)alloc((size_t)NP * 4);
    float* deg_in_inv = (float*)alloc((size_t)NP * 4);
    int* pairA = (int*)alloc((size_t)NBUCK * BCAP * 4);
    int* pairB = (int*)alloc((size_t)NBUCKD * BCAPD * 4);
    int* pairB2 = (int*)alloc((size_t)NBUCKD * 32 * SCAP * 4);
    int* fillS = (int*)alloc((size_t)NBUCKD * 32 * 4);
    int* cntB = (int*)alloc((size_t)NBUCK * NBUCKD * 4);
    int* offB = (int*)alloc((size_t)NBUCK * NBUCKD * 4);
    int* fillB = (int*)alloc((size_t)NBUCKD * 4);
    ushort* Wp1 = (ushort*)alloc((size_t)2 * 4 * 16 * 512 * 2);   // K=128,M=256 hi/lo
    ushort* Wp2 = (ushort*)alloc((size_t)2 * 8 * 16 * 512 * 2);   // K=256,M=256
    ushort* Wp3 = (ushort*)alloc((size_t)2 * 8 * 8 * 512 * 2);    // K=256,M=128
    ushort* featb = (ushort*)alloc((size_t)NP * 128 * 2);   // feat*deg_out, bf16
    ushort* aggb  = (ushort*)alloc((size_t)NP * 256 * 2);   // aggregation output (reused)
    ushort* hb    = (ushort*)alloc((size_t)NP * 256 * 2);   // h*deg_out, bf16 (reused)
    ushort* yb    = (ushort*)alloc((size_t)NP * 128 * 2);   // layer-3 GEMM output
    (void)ws_size; (void)in_sizes; (void)n_in; (void)out_size;

    // graph build: src-bucket partition -> deterministic dst partition (src-ordered)
    // -> per-bucket stable split into 32 row-disjoint sub-lists -> degrees
    k_init_cur<<<2, 256, 0, stream>>>(curA);
    k_partA<<<PBLK, 256, 0, stream>>>(src, dst, curA, pairA);
    k_degout<<<NBUCK, 256, 0, stream>>>(curA, pairA, deg_out_inv);
    k_countB<<<NBUCK, 256, 0, stream>>>(curA, pairA, cntB);
    k_scanB<<<NBUCKD, 512, 0, stream>>>(cntB, offB, fillB);
    k_placeB<<<NBUCK, 256, 0, stream>>>(curA, pairA, offB, pairB);
    k_deg_in<<<NBUCKD, 256, 0, stream>>>(fillB, pairB, deg_in_inv);
    k_split32<<<NBUCKD, 512, 0, stream>>>(fillB, pairB, pairB2, fillS);

    // weights -> MFMA fragment order (hi/lo planes); feat -> bf16 with deg_out fold
    k_packAll<<<64, 256, 0, stream>>>(W1, Wp1, W2, Wp2, W3, Wp3);
    k_cvt<<<(NN * 32 + 255) / 256, 256, 0, stream>>>(feat, deg_out_inv, featb);

    // layer 1: push-agg(feat*deg_out) -> GEMM 128->256 [+b1,*deg_in,LN,PReLU,*deg_out] -> hb
    k_agg_push3<128, 0, false><<<NBUCKD, 1024, 0, stream>>>(pairB2, fillS, featb, nullptr, nullptr, aggb, nullptr);
    k_gemm_mfma<128, 256, 1><<<NP / 64, 256, 0, stream>>>(aggb, Wp1, b1, deg_in_inv, deg_out_inv, g1, be1, a1, hb);

    // layer 2: push-agg(h1*deg_out) in two 128-col passes -> GEMM 256->256 [epilogue] -> hb
    k_agg_push3<256, 0, false><<<NBUCKD, 1024, 0, stream>>>(pairB2, fillS, hb, nullptr, nullptr, aggb, nullptr);
    k_agg_push3<256, 128, false><<<NBUCKD, 1024, 0, stream>>>(pairB2, fillS, hb, nullptr, nullptr, aggb, nullptr);
    k_gemm_mfma<256, 256, 1><<<NP / 64, 256, 0, stream>>>(aggb, Wp2, b2, deg_in_inv, deg_out_inv, g2, be2, a2, hb);

    // layer 3: GEMM (h2*deg_out)@W3 -> yb, then push-agg(yb) with (+b3)*deg_in into d_out
    k_gemm_mfma<256, 128, 0><<<NP / 128, 256, 0, stream>>>(hb, Wp3, nullptr, nullptr, nullptr, nullptr, nullptr, nullptr, yb);
    k_agg_push3<128, 0, true><<<NBUCKD, 1024, 0, stream>>>(pairB2, fillS, yb, b3, deg_in_inv, nullptr, (float*)d_out);
}